// Round 2
// baseline (1101.965 us; speedup 1.0000x reference)
//
#include <hip/hip_runtime.h>
#include <hip/hip_bf16.h>
#include <math.h>

#define BB 4
#define CC 96
#define LL 1600
#define DD 192
#define KK 4
#define RR 6
#define NN 16
#define EE 4
#define NCH 16
#define CLEN 100

typedef __hip_bfloat16 bf16;

__device__ __forceinline__ float geluf(float x){ return 0.5f*x*(1.0f+erff(x*0.70710678118654752440f)); }
__device__ __forceinline__ float softplusf(float x){ return (x>20.0f)? x : log1pf(__expf(x)); }
#define BNS rsqrtf(1.0f + 1e-5f)

// permutation map: index into xx (hw-order) for scan-direction k at scan index l
__device__ __forceinline__ int xpos(int k, int l){
  if (k==0) return l;
  if (k==2) return LL-1-l;
  int t = (k==1)? l : (LL-1-l);
  return (t%40)*40 + t/40;   // H==W==40: wh<->hw transpose map (involution)
}

// ---- input conversion: everything -> fp32 in workspace ----
struct P33 { const void* p[33]; };
#define NTOT 790660
__device__ const int g_cum[34] = {
  0, 614400, 623616, 623712, 623808, 624672, 624768, 624864, 624960,
  634176, 634272, 643488, 643584, 643680, 643776, 680640, 682368, 682560,
  711744, 716352, 717120, 729408, 730176, 730368, 730560, 748992, 749088,
  749184, 749568, 749572, 753028, 753412, 790276, 790660
};

__global__ void k_convert(P33 ps, float* cv){
  // Ds is ones: fp32 -> first dword 0x3F800000 ; bf16 -> 0x3F803F80
  bool f32 = (((const unsigned*)ps.p[21])[0] == 0x3F800000u);
  int idx = blockIdx.x*256 + threadIdx.x;
  if (idx >= NTOT) return;
  int lo=0, hi=33;
  while (lo+1<hi){ int mid=(lo+hi)>>1; if (idx >= g_cum[mid]) lo=mid; else hi=mid; }
  int local = idx - g_cum[lo];
  float v = f32 ? ((const float*)ps.p[lo])[local]
                : __bfloat162float(((const bf16*)ps.p[lo])[local]);
  cv[idx] = v;
}

// 1: x = silu(bn0(conv1x1(x, proj_w)))
__global__ void k_proj(const float* x, const float* w, const float* g, const float* b_, float* out){
  int idx = blockIdx.x*256 + threadIdx.x;
  if (idx >= BB*CC*LL) return;
  int l = idx % LL, o = (idx/LL)%CC, b = idx/(LL*CC);
  const float* xp = x + b*CC*LL + l;
  const float* wp = w + o*CC;
  float acc = 0.f;
  #pragma unroll 8
  for (int c=0;c<CC;c++) acc += wp[c]*xp[c*LL];
  float v = acc*(g[o]*BNS) + b_[o];
  out[idx] = v/(1.0f+__expf(-v));
}

// 2: h = bn(dwconv3(R, fc1_w, fc1_b))
__global__ void k_dwbn(const float* in, const float* w, const float* bias, const float* g, const float* b_, float* out){
  int idx = blockIdx.x*256 + threadIdx.x;
  if (idx >= BB*CC*LL) return;
  int l = idx%LL, c = (idx/LL)%CC, b = idx/(LL*CC);
  int y = l/40, x0 = l%40;
  const float* ip = in + (b*CC+c)*LL;
  float acc = 0.f;
  #pragma unroll
  for (int ky=0;ky<3;ky++){
    int yy = y+ky-1; if (yy<0||yy>=40) continue;
    #pragma unroll
    for (int kx=0;kx<3;kx++){
      int xx = x0+kx-1; if (xx<0||xx>=40) continue;
      acc += w[c*9+ky*3+kx] * ip[yy*40+xx];
    }
  }
  acc += bias[c];
  out[idx] = acc*(g[c]*BNS) + b_[c];
}

// 3: gelu(conv1x1 + bias)
__global__ void k_fc_gelu(const float* in, const float* w, const float* bias, float* out){
  int idx = blockIdx.x*256 + threadIdx.x;
  if (idx >= BB*CC*LL) return;
  int l = idx%LL, o = (idx/LL)%CC, b = idx/(LL*CC);
  const float* ip = in + b*CC*LL + l;
  const float* wp = w + o*CC;
  float acc = bias[o];
  #pragma unroll 8
  for (int c=0;c<CC;c++) acc += wp[c]*ip[c*LL];
  out[idx] = geluf(acc);
}

// 4: X1 = bn_n1( res + conv1x1(in) + bias )
__global__ void k_fc_res_bn(const float* in, const float* w, const float* bias, const float* res,
                            const float* g, const float* b_, float* out){
  int idx = blockIdx.x*256 + threadIdx.x;
  if (idx >= BB*CC*LL) return;
  int l = idx%LL, o = (idx/LL)%CC, b = idx/(LL*CC);
  const float* ip = in + b*CC*LL + l;
  const float* wp = w + o*CC;
  float acc = bias[o];
  #pragma unroll 8
  for (int c=0;c<CC;c++) acc += wp[c]*ip[c*LL];
  float v = acc + res[idx];
  out[idx] = v*(g[o]*BNS) + b_[o];
}

// 5: xz = conv1x1(X1, in_proj_w); split into xx_pre and z1=gelu(z)
__global__ void k_inproj(const float* in, const float* w, float* xxp, float* z1){
  int idx = blockIdx.x*256 + threadIdx.x;
  if (idx >= BB*2*DD*LL) return;
  int l = idx%LL, oc = (idx/LL)%(2*DD), b = idx/(LL*2*DD);
  const float* ip = in + b*CC*LL + l;
  const float* wp = w + oc*CC;
  float acc = 0.f;
  #pragma unroll 8
  for (int c=0;c<CC;c++) acc += wp[c]*ip[c*LL];
  if (oc < DD) xxp[(b*DD+oc)*LL+l] = acc;
  else         z1[(b*DD+(oc-DD))*LL+l] = geluf(acc);
}

// 6: xx = gelu(dwconv3(xx_pre, conv_w, conv_b))
__global__ void k_ssconv(const float* in, const float* w, const float* bias, float* out){
  int idx = blockIdx.x*256 + threadIdx.x;
  if (idx >= BB*DD*LL) return;
  int l = idx%LL, d = (idx/LL)%DD, b = idx/(LL*DD);
  int y = l/40, x0 = l%40;
  const float* ip = in + (b*DD+d)*LL;
  float acc = 0.f;
  #pragma unroll
  for (int ky=0;ky<3;ky++){
    int yy = y+ky-1; if (yy<0||yy>=40) continue;
    #pragma unroll
    for (int kx=0;kx<3;kx++){
      int xx = x0+kx-1; if (xx<0||xx>=40) continue;
      acc += w[d*9+ky*3+kx] * ip[yy*40+xx];
    }
  }
  out[idx] = geluf(acc + bias[d]);
}

// 7: x_dbl = einsum over d; split into dts_r / Bs / Cs
__global__ void k_xdbl(const float* xx, const float* xw, float* dtsR, float* Bs, float* Cs){
  int idx = blockIdx.x*256 + threadIdx.x;
  if (idx >= BB*KK*38*LL) return;
  int l = idx%LL, c38 = (idx/LL)%38, k = (idx/(LL*38))%KK, b = idx/(LL*38*KK);
  int p = xpos(k,l);
  const float* ip = xx + b*DD*LL + p;
  const float* wp = xw + (k*38+c38)*DD;
  float acc = 0.f;
  #pragma unroll 8
  for (int d=0;d<DD;d++) acc += wp[d]*ip[d*LL];
  int bk = b*KK+k;
  if (c38 < RR)          dtsR[(bk*RR+c38)*LL+l] = acc;
  else if (c38 < RR+NN)  Bs[(bk*NN+(c38-RR))*LL+l] = acc;
  else                   Cs[(bk*NN+(c38-RR-NN))*LL+l] = acc;
}

// 8: dts = softplus(einsum(dts_r, dt_w) + dt_b)
__global__ void k_dt(const float* dtsR, const float* dtw, const float* dtb, float* dts){
  int idx = blockIdx.x*256 + threadIdx.x;
  if (idx >= BB*KK*DD*LL) return;
  int l = idx%LL, d = (idx/LL)%DD, k = (idx/(LL*DD))%KK, b = idx/(LL*DD*KK);
  int bk = b*KK+k;
  const float* rp = dtsR + bk*RR*LL + l;
  const float* wp = dtw + (k*DD+d)*RR;
  float acc = dtb[k*DD+d];
  #pragma unroll
  for (int r=0;r<RR;r++) acc += wp[r]*rp[r*LL];
  dts[(bk*DD+d)*LL+l] = softplusf(acc);
}

// 9: scan pass1 — per (b,k,d,chunk): P = prod dA, S = zero-init state at chunk end
__global__ void k_scan1(const float* dts, const float* xx, const float* Bs, const float* Alog,
                        float* Pb, float* Sb){
  int idx = blockIdx.x*256 + threadIdx.x;
  if (idx >= BB*KK*NCH*DD) return;
  int d = idx%DD, c = (idx/DD)%NCH, bk = idx/(DD*NCH);
  int k = bk%KK, b = bk/KK;
  float A[NN], P[NN], S[NN];
  #pragma unroll
  for (int n=0;n<NN;n++){ A[n] = -expf(Alog[(k*DD+d)*NN+n]); P[n]=1.f; S[n]=0.f; }
  const float* dtp   = dts + (bk*DD+d)*LL + c*CLEN;
  const float* xbase = xx  + b*DD*LL + d*LL;
  const float* Bp    = Bs  + bk*NN*LL + c*CLEN;
  for (int j=0;j<CLEN;j++){
    float dt = dtp[j];
    float xv = xbase[xpos(k, c*CLEN+j)];
    float u = dt*xv;
    #pragma unroll
    for (int n=0;n<NN;n++){
      float dA = __expf(dt*A[n]);
      P[n] *= dA;
      S[n] = S[n]*dA + u*Bp[n*LL+j];
    }
  }
  int off = ((bk*DD+d)*NCH + c)*NN;
  #pragma unroll
  for (int n=0;n<NN;n++){ Pb[off+n]=P[n]; Sb[off+n]=S[n]; }
}

// 10: inter-chunk scan per (b,k,d,n): Hin[c] = state entering chunk c
__global__ void k_scanmid(const float* Pb, const float* Sb, float* Hin){
  int idx = blockIdx.x*256 + threadIdx.x;
  if (idx >= BB*KK*DD*NN) return;
  int n = idx%NN, bkd = idx/NN;
  float h = 0.f;
  for (int c=0;c<NCH;c++){
    int o = (bkd*NCH + c)*NN + n;
    Hin[o] = h;
    h = Pb[o]*h + Sb[o];
  }
}

// 11: scan pass2 — replay with carry-in, atomically accumulate into combined Y (hw-order)
__global__ void k_scan2(const float* dts, const float* xx, const float* Bs, const float* Cs,
                        const float* Hin, const float* Alog, const float* Ds, float* Y){
  int idx = blockIdx.x*256 + threadIdx.x;
  if (idx >= BB*KK*NCH*DD) return;
  int d = idx%DD, c = (idx/DD)%NCH, bk = idx/(DD*NCH);
  int k = bk%KK, b = bk/KK;
  int bkd = bk*DD+d;
  float A[NN], h[NN];
  #pragma unroll
  for (int n=0;n<NN;n++){
    A[n] = -expf(Alog[(k*DD+d)*NN+n]);
    h[n] = Hin[(bkd*NCH+c)*NN+n];
  }
  float Dv = Ds[k*DD+d];
  const float* dtp   = dts + bkd*LL + c*CLEN;
  const float* xbase = xx  + b*DD*LL + d*LL;
  const float* Bp    = Bs  + bk*NN*LL + c*CLEN;
  const float* Cp    = Cs  + bk*NN*LL + c*CLEN;
  float* yb = Y + (b*DD+d)*LL;
  for (int j=0;j<CLEN;j++){
    int p = xpos(k, c*CLEN+j);
    float dt = dtp[j];
    float xv = xbase[p];
    float u = dt*xv;
    float y = 0.f;
    #pragma unroll
    for (int n=0;n<NN;n++){
      float dA = __expf(dt*A[n]);
      h[n] = h[n]*dA + u*Bp[n*LL+j];
      y += h[n]*Cp[n*LL+j];
    }
    atomicAdd(&yb[p], y + Dv*xv);
  }
}

// 13: layernorm over channels (per b,l) * onorm, then * z1
__global__ void k_ln(const float* y, const float* og, const float* ob, const float* z1, float* out){
  int idx = blockIdx.x*256 + threadIdx.x;
  if (idx >= BB*LL) return;
  int l = idx%LL, b = idx/LL;
  const float* yp = y + b*DD*LL + l;
  float m = 0.f;
  for (int d=0;d<DD;d++) m += yp[d*LL];
  m *= (1.0f/DD);
  float v = 0.f;
  for (int d=0;d<DD;d++){ float t = yp[d*LL]-m; v += t*t; }
  v *= (1.0f/DD);
  float rs = rsqrtf(v + 1e-5f);
  for (int d=0;d<DD;d++){
    float t = (yp[d*LL]-m)*rs*og[d] + ob[d];
    out[(b*DD+d)*LL+l] = t * z1[(b*DD+d)*LL+l];
  }
}

// 14: x2 = res1 + conv1x1(yz, out_proj_w); xb = bn_n2(x2)
__global__ void k_outproj(const float* yz, const float* w, const float* res, const float* g, const float* b_,
                          float* x2, float* xb){
  int idx = blockIdx.x*256 + threadIdx.x;
  if (idx >= BB*CC*LL) return;
  int l = idx%LL, o = (idx/LL)%CC, b = idx/(LL*CC);
  const float* ip = yz + b*DD*LL + l;
  const float* wp = w + o*DD;
  float acc = 0.f;
  #pragma unroll 8
  for (int d=0;d<DD;d++) acc += wp[d]*ip[d*LL];
  float v = res[idx] + acc;
  x2[idx] = v;
  xb[idx] = v*(g[o]*BNS) + b_[o];
}

// 15: spatial mean per (b,c)
__global__ void k_gmean(const float* xb, float* gv){
  int idx = blockIdx.x*256 + threadIdx.x;
  if (idx >= BB*CC) return;
  const float* p = xb + idx*LL;
  float s = 0.f;
  for (int l=0;l<LL;l++) s += p[l];
  gv[idx] = s*(1.0f/LL);
}

// 16: router: logits, softmax(/2), top-2, renormalize -> wmat (B,E)
__global__ void k_router(const float* gv, const float* rw, const float* rb, float* wm){
  int b = threadIdx.x;
  if (b >= BB) return;
  float lg[EE];
  for (int e=0;e<EE;e++){
    float a = rb[e];
    for (int c=0;c<CC;c++) a += gv[b*CC+c]*rw[e*CC+c];
    lg[e] = a*0.5f;
  }
  float mx = lg[0];
  for (int e=1;e<EE;e++) mx = fmaxf(mx, lg[e]);
  float p[EE], s = 0.f;
  for (int e=0;e<EE;e++){ p[e] = __expf(lg[e]-mx); s += p[e]; }
  for (int e=0;e<EE;e++) p[e] /= s;
  int i1 = 0;
  for (int e=1;e<EE;e++) if (p[e] > p[i1]) i1 = e;
  int i2 = -1;
  for (int e=0;e<EE;e++){ if (e==i1) continue; if (i2<0 || p[e]>p[i2]) i2 = e; }
  float tot = p[i1]+p[i2];
  for (int e=0;e<EE;e++) wm[b*EE+e] = 0.f;
  wm[b*EE+i1] = p[i1]/tot;
  wm[b*EE+i2] = p[i2]/tot;
}

// 17: per-expert dwconv+gelu (skip unselected experts)
__global__ void k_moedw(const float* xb, const float* dw, const float* db, const float* wm, float* he){
  int idx = blockIdx.x*256 + threadIdx.x;
  if (idx >= EE*BB*CC*LL) return;
  int l = idx%LL, c = (idx/LL)%CC, b = (idx/(LL*CC))%BB, e = idx/(LL*CC*BB);
  if (wm[b*EE+e] == 0.f) return;
  int y = l/40, x0 = l%40;
  const float* ip = xb + (b*CC+c)*LL;
  float acc = 0.f;
  #pragma unroll
  for (int ky=0;ky<3;ky++){
    int yy = y+ky-1; if (yy<0||yy>=40) continue;
    #pragma unroll
    for (int kx=0;kx<3;kx++){
      int xx = x0+kx-1; if (xx<0||xx>=40) continue;
      acc += dw[(e*CC+c)*9+ky*3+kx] * ip[yy*40+xx];
    }
  }
  he[((e*BB+b)*CC+c)*LL+l] = geluf(acc + db[e*CC+c]);
}

// 18: out = x2 + sum_e wm[b,e]*(conv1x1(he_e, pw_e) + pb_e), store per detected dtype
__global__ void k_final(const float* he, const float* pw, const float* pb, const float* wm,
                        const float* x2, void* out, const void* dsraw){
  bool f32 = (((const unsigned*)dsraw)[0] == 0x3F800000u);
  int idx = blockIdx.x*256 + threadIdx.x;
  if (idx >= BB*CC*LL) return;
  int l = idx%LL, o = (idx/LL)%CC, b = idx/(LL*CC);
  float acc = x2[idx];
  for (int e=0;e<EE;e++){
    float wv = wm[b*EE+e];
    if (wv == 0.f) continue;
    const float* hp = he + (e*BB+b)*CC*LL + l;
    const float* wp = pw + (e*CC+o)*CC;
    float s = pb[e*CC+o];
    #pragma unroll 8
    for (int c=0;c<CC;c++) s += wp[c]*hp[c*LL];
    acc += wv*s;
  }
  if (f32) ((float*)out)[idx] = acc;
  else     ((bf16*)out)[idx] = __float2bfloat16(acc);
}

extern "C" void kernel_launch(void* const* d_in, const int* in_sizes, int n_in,
                              void* d_out, int out_size, void* d_ws, size_t ws_size,
                              hipStream_t stream) {
  static const int cum[34] = {
    0, 614400, 623616, 623712, 623808, 624672, 624768, 624864, 624960,
    634176, 634272, 643488, 643584, 643680, 643776, 680640, 682368, 682560,
    711744, 716352, 717120, 729408, 730176, 730368, 730560, 748992, 749088,
    749184, 749568, 749572, 753028, 753412, 790276, 790660
  };
  float* ws = (float*)d_ws;
  const float* cv[33];
  P33 ps;
  for (int i=0;i<33;i++){ ps.p[i] = d_in[i]; cv[i] = ws + cum[i]; }

  const float* c_x    = cv[0];
  const float* c_pw   = cv[1];
  const float* c_bn0g = cv[2];
  const float* c_bn0b = cv[3];
  const float* c_f1w  = cv[4];
  const float* c_f1b  = cv[5];
  const float* c_lbg  = cv[6];
  const float* c_lbb  = cv[7];
  const float* c_f2w  = cv[8];
  const float* c_f2b  = cv[9];
  const float* c_f3w  = cv[10];
  const float* c_f3b  = cv[11];
  const float* c_n1g  = cv[12];
  const float* c_n1b  = cv[13];
  const float* c_ipw  = cv[14];
  const float* c_cw   = cv[15];
  const float* c_cb   = cv[16];
  const float* c_xpw  = cv[17];
  const float* c_dtw  = cv[18];
  const float* c_dtb  = cv[19];
  const float* c_al   = cv[20];
  const float* c_ds   = cv[21];
  const float* c_ong  = cv[22];
  const float* c_onb  = cv[23];
  const float* c_opw  = cv[24];
  const float* c_n2g  = cv[25];
  const float* c_n2b  = cv[26];
  const float* c_rw   = cv[27];
  const float* c_rb   = cv[28];
  const float* c_mdw  = cv[29];
  const float* c_mdb  = cv[30];
  const float* c_mpw  = cv[31];
  const float* c_mpb  = cv[32];

  // aliased arena (floats); total 14,423,296 floats = 57.7 MB
  float* R   = ws +   800000;  // 614400, live to k_outproj
  float* T1  = ws +  1414400;  // slot A: T1 -> X1 -> X2
  float* X1  = T1;
  float* X2  = T1;
  float* T2  = ws +  2028800;  // slot B: T2 -> DTR -> XB
  float* DTR = T2;
  float* XB  = T2;
  float* XXP = ws +  2643200;  // slot C: XXP -> Y (1228800)
  float* Y   = XXP;
  float* Z1  = ws +  3872000;  // slot D: Z1 -> HE (HE spans D+E = 2457600)
  float* HE  = Z1;
  float* XX  = ws +  5100800;  // slot E: XX
  float* BS  = ws +  6329600;  // slot F: BS -> GV/WM
  float* GV  = BS;
  float* WM  = BS + 384;
  float* CS  = ws +  6739200;  // slot G
  float* DTS = ws +  7148800;  // slot H: DTS (4915200) -> YZ
  float* YZ  = DTS;
  float* PB  = ws + 12064000;  // 786432
  float* SB  = ws + 12850432;  // 786432
  float* HIN = ws + 13636864;  // 786432

  const int T = 256;
  k_convert  <<<(NTOT+T-1)/T, T, 0, stream>>>(ps, ws);
  k_proj     <<<(BB*CC*LL+T-1)/T, T, 0, stream>>>(c_x, c_pw, c_bn0g, c_bn0b, R);
  k_dwbn     <<<(BB*CC*LL+T-1)/T, T, 0, stream>>>(R, c_f1w, c_f1b, c_lbg, c_lbb, T1);
  k_fc_gelu  <<<(BB*CC*LL+T-1)/T, T, 0, stream>>>(T1, c_f2w, c_f2b, T2);
  k_fc_res_bn<<<(BB*CC*LL+T-1)/T, T, 0, stream>>>(T2, c_f3w, c_f3b, R, c_n1g, c_n1b, X1);
  k_inproj   <<<(BB*2*DD*LL+T-1)/T, T, 0, stream>>>(X1, c_ipw, XXP, Z1);
  k_ssconv   <<<(BB*DD*LL+T-1)/T, T, 0, stream>>>(XXP, c_cw, c_cb, XX);
  hipMemsetAsync(Y, 0, (size_t)BB*DD*LL*sizeof(float), stream);   // Y aliases XXP (now dead)
  k_xdbl     <<<(BB*KK*38*LL+T-1)/T, T, 0, stream>>>(XX, c_xpw, DTR, BS, CS);
  k_dt       <<<(BB*KK*DD*LL+T-1)/T, T, 0, stream>>>(DTR, c_dtw, c_dtb, DTS);
  k_scan1    <<<(BB*KK*NCH*DD+T-1)/T, T, 0, stream>>>(DTS, XX, BS, c_al, PB, SB);
  k_scanmid  <<<(BB*KK*DD*NN+T-1)/T, T, 0, stream>>>(PB, SB, HIN);
  k_scan2    <<<(BB*KK*NCH*DD+T-1)/T, T, 0, stream>>>(DTS, XX, BS, CS, HIN, c_al, c_ds, Y);
  k_ln       <<<(BB*LL+T-1)/T, T, 0, stream>>>(Y, c_ong, c_onb, Z1, YZ);
  k_outproj  <<<(BB*CC*LL+T-1)/T, T, 0, stream>>>(YZ, c_opw, R, c_n2g, c_n2b, X2, XB);
  k_gmean    <<<(BB*CC+T-1)/T, T, 0, stream>>>(XB, GV);
  k_router   <<<1, 64, 0, stream>>>(GV, c_rw, c_rb, WM);
  k_moedw    <<<(EE*BB*CC*LL+T-1)/T, T, 0, stream>>>(XB, c_mdw, c_mdb, WM, HE);
  k_final    <<<(BB*CC*LL+T-1)/T, T, 0, stream>>>(HE, c_mpw, c_mpb, WM, X2, d_out, d_in[21]);
}

// Round 3
// 581.374 us; speedup vs baseline: 1.8955x; 1.8955x over previous
//
#include <hip/hip_runtime.h>
#include <hip/hip_bf16.h>
#include <math.h>

#define BB 4
#define CC 96
#define LL 1600
#define DD 192
#define KK 4
#define RR 6
#define NN 16
#define EE 4
#define NCH 40
#define CLEN 40

typedef __hip_bfloat16 bf16;

__device__ __forceinline__ float geluf(float x){ return 0.5f*x*(1.0f+erff(x*0.70710678118654752440f)); }
__device__ __forceinline__ float softplusf(float x){ return (x>20.0f)? x : log1pf(__expf(x)); }
#define BNS rsqrtf(1.0f + 1e-5f)

// hw position for scan-direction k at scan index t
__device__ __forceinline__ int xpos(int k, int l){
  if (k==0) return l;
  if (k==2) return LL-1-l;
  int t = (k==1)? l : (LL-1-l);
  return (t%40)*40 + t/40;   // H==W==40 transpose map (involution)
}

// ---- input conversion: everything -> fp32 in workspace ----
struct P33 { const void* p[33]; };
#define NTOT 790660
__device__ const int g_cum[34] = {
  0, 614400, 623616, 623712, 623808, 624672, 624768, 624864, 624960,
  634176, 634272, 643488, 643584, 643680, 643776, 680640, 682368, 682560,
  711744, 716352, 717120, 729408, 730176, 730368, 730560, 748992, 749088,
  749184, 749568, 749572, 753028, 753412, 790276, 790660
};

__global__ void k_convert(P33 ps, float* cv){
  // Ds is ones: fp32 -> first dword 0x3F800000 ; bf16 -> 0x3F803F80
  bool f32 = (((const unsigned*)ps.p[21])[0] == 0x3F800000u);
  int idx = blockIdx.x*256 + threadIdx.x;
  if (idx >= NTOT) return;
  int lo=0, hi=33;
  while (lo+1<hi){ int mid=(lo+hi)>>1; if (idx >= g_cum[mid]) lo=mid; else hi=mid; }
  int local = idx - g_cum[lo];
  float v = f32 ? ((const float*)ps.p[lo])[local]
                : __bfloat162float(((const bf16*)ps.p[lo])[local]);
  cv[idx] = v;
}

// 1: x = silu(bn0(conv1x1(x, proj_w)))  [4-way o-tile]
__global__ void k_proj(const float* x, const float* w, const float* g, const float* b_, float* out){
  int idx = blockIdx.x*256 + threadIdx.x;
  if (idx >= BB*24*LL) return;
  int l = idx%LL, og = (idx/LL)%24, b = idx/(LL*24);
  const float* xp = x + b*CC*LL + l;
  float acc[4] = {0.f,0.f,0.f,0.f};
  for (int c=0;c<CC;c++){
    float xv = xp[c*LL];
    #pragma unroll
    for (int j=0;j<4;j++) acc[j] += w[(og+24*j)*CC+c]*xv;
  }
  #pragma unroll
  for (int j=0;j<4;j++){
    int o = og+24*j;
    float v = acc[j]*(g[o]*BNS) + b_[o];
    out[(b*CC+o)*LL+l] = v/(1.0f+__expf(-v));
  }
}

// 2: h = bn(dwconv3(R, fc1_w, fc1_b))
__global__ void k_dwbn(const float* in, const float* w, const float* bias, const float* g, const float* b_, float* out){
  int idx = blockIdx.x*256 + threadIdx.x;
  if (idx >= BB*CC*LL) return;
  int l = idx%LL, c = (idx/LL)%CC, b = idx/(LL*CC);
  int y = l/40, x0 = l%40;
  const float* ip = in + (b*CC+c)*LL;
  float acc = 0.f;
  #pragma unroll
  for (int ky=0;ky<3;ky++){
    int yy = y+ky-1; if (yy<0||yy>=40) continue;
    #pragma unroll
    for (int kx=0;kx<3;kx++){
      int xx = x0+kx-1; if (xx<0||xx>=40) continue;
      acc += w[c*9+ky*3+kx] * ip[yy*40+xx];
    }
  }
  acc += bias[c];
  out[idx] = acc*(g[c]*BNS) + b_[c];
}

// 3: gelu(conv1x1 + bias)  [4-way o-tile]
__global__ void k_fc_gelu(const float* in, const float* w, const float* bias, float* out){
  int idx = blockIdx.x*256 + threadIdx.x;
  if (idx >= BB*24*LL) return;
  int l = idx%LL, og = (idx/LL)%24, b = idx/(LL*24);
  const float* ip = in + b*CC*LL + l;
  float acc[4];
  #pragma unroll
  for (int j=0;j<4;j++) acc[j] = bias[og+24*j];
  for (int c=0;c<CC;c++){
    float xv = ip[c*LL];
    #pragma unroll
    for (int j=0;j<4;j++) acc[j] += w[(og+24*j)*CC+c]*xv;
  }
  #pragma unroll
  for (int j=0;j<4;j++) out[(b*CC+og+24*j)*LL+l] = geluf(acc[j]);
}

// 4: X1 = bn_n1( res + conv1x1(in) + bias )  [4-way o-tile]
__global__ void k_fc_res_bn(const float* in, const float* w, const float* bias, const float* res,
                            const float* g, const float* b_, float* out){
  int idx = blockIdx.x*256 + threadIdx.x;
  if (idx >= BB*24*LL) return;
  int l = idx%LL, og = (idx/LL)%24, b = idx/(LL*24);
  const float* ip = in + b*CC*LL + l;
  float acc[4];
  #pragma unroll
  for (int j=0;j<4;j++) acc[j] = bias[og+24*j];
  for (int c=0;c<CC;c++){
    float xv = ip[c*LL];
    #pragma unroll
    for (int j=0;j<4;j++) acc[j] += w[(og+24*j)*CC+c]*xv;
  }
  #pragma unroll
  for (int j=0;j<4;j++){
    int o = og+24*j;
    float v = acc[j] + res[(b*CC+o)*LL+l];
    out[(b*CC+o)*LL+l] = v*(g[o]*BNS) + b_[o];
  }
}

// 5: xz = conv1x1(X1, in_proj_w); oc<192 -> xxp, else z1=gelu  [4-way tile]
__global__ void k_inproj(const float* in, const float* w, float* xxp, float* z1){
  int idx = blockIdx.x*256 + threadIdx.x;
  if (idx >= BB*96*LL) return;
  int l = idx%LL, og = (idx/LL)%96, b = idx/(LL*96);
  const float* ip = in + b*CC*LL + l;
  float acc[4] = {0.f,0.f,0.f,0.f};
  for (int c=0;c<CC;c++){
    float xv = ip[c*LL];
    #pragma unroll
    for (int j=0;j<4;j++) acc[j] += w[(og+96*j)*CC+c]*xv;
  }
  xxp[(b*DD+og)*LL+l]      = acc[0];
  xxp[(b*DD+og+96)*LL+l]   = acc[1];
  z1[(b*DD+og)*LL+l]       = geluf(acc[2]);
  z1[(b*DD+og+96)*LL+l]    = geluf(acc[3]);
}

// 6: xx = gelu(dwconv3(xx_pre, conv_w, conv_b))
__global__ void k_ssconv(const float* in, const float* w, const float* bias, float* out){
  int idx = blockIdx.x*256 + threadIdx.x;
  if (idx >= BB*DD*LL) return;
  int l = idx%LL, d = (idx/LL)%DD, b = idx/(LL*DD);
  int y = l/40, x0 = l%40;
  const float* ip = in + (b*DD+d)*LL;
  float acc = 0.f;
  #pragma unroll
  for (int ky=0;ky<3;ky++){
    int yy = y+ky-1; if (yy<0||yy>=40) continue;
    #pragma unroll
    for (int kx=0;kx<3;kx++){
      int xx = x0+kx-1; if (xx<0||xx>=40) continue;
      acc += w[d*9+ky*3+kx] * ip[yy*40+xx];
    }
  }
  out[idx] = geluf(acc + bias[d]);
}

// 6b: LDS-tiled transpose -> XS (b,k01,l,d); k01=0 scan rows = l, k01=1 rows = transpose(l)
__global__ void k_xs(const float* xx, float* xs){
  __shared__ float t[32][33];
  int bid = blockIdx.x;
  int lt = bid % 50, dt = (bid/50)%6, b = bid/300;
  int l0 = lt*32, d0 = dt*32;
  int tx = threadIdx.x & 31, ty = threadIdx.x >> 5;   // tx: 0..31, ty: 0..7
  #pragma unroll
  for (int j=0;j<4;j++){
    int dd = ty + 8*j;
    t[dd][tx] = xx[(b*DD + d0+dd)*LL + l0 + tx];
  }
  __syncthreads();
  #pragma unroll
  for (int j=0;j<4;j++){
    int ll = ty + 8*j;
    int l = l0 + ll;
    float v = t[tx][ll];
    int lw = (l%40)*40 + l/40;
    xs[((b*2+0)*LL + l )*DD + d0 + tx] = v;
    xs[((b*2+1)*LL + lw)*DD + d0 + tx] = v;
  }
}

// 7: x_dbl (bk,l,38) = sum_d xw[k][c][d] * XS[bk-row][d]
__global__ void k_xdbl(const float* xs, const float* xw, float* xd){
  int idx = blockIdx.x*256 + threadIdx.x;
  if (idx >= BB*KK*LL*38) return;
  int c38 = idx%38, l = (idx/38)%LL, bk = idx/(38*LL);
  int k = bk%KK, b = bk/KK;
  int k01 = k&1;
  int row = (k<2)? l : (LL-1-l);
  const float* xp = xs + ((b*2+k01)*LL + row)*DD;
  const float* wp = xw + (k*38 + c38)*DD;
  float acc = 0.f;
  #pragma unroll 8
  for (int d=0;d<DD;d++) acc += wp[d]*xp[d];
  xd[idx] = acc;
}

// 9: scan pass1 — per (b,k,chunk,d): P = prod dA, S = zero-init chunk-end state
__global__ void k_scan1(const float* xs, const float* xd, const float* dtw, const float* dtb,
                        const float* Alog, float* Pb, float* Sb){
  int idx = blockIdx.x*256 + threadIdx.x;
  if (idx >= BB*KK*NCH*DD) return;
  int d = idx%DD, c = (idx/DD)%NCH, bk = idx/(DD*NCH);
  int k = bk%KK, b = bk/KK;
  int kd = k*DD+d;
  float w6[RR];
  #pragma unroll
  for (int r=0;r<RR;r++) w6[r] = dtw[kd*RR+r];
  float bias = dtb[kd];
  float A[NN], P[NN], S[NN];
  #pragma unroll
  for (int n=0;n<NN;n++){ A[n] = -expf(Alog[kd*NN+n]); P[n]=1.f; S[n]=0.f; }
  int k01 = k&1;
  const float* xsb = xs + (b*2+k01)*LL*DD;
  const float* xdb = xd + bk*LL*38;
  bool rev = (k>=2);
  for (int j=0;j<CLEN;j++){
    int t = c*CLEN + j;
    int row = rev ? (LL-1-t) : t;
    const float* xdr = xdb + t*38;
    float dtr = bias;
    #pragma unroll
    for (int r=0;r<RR;r++) dtr += w6[r]*xdr[r];
    float dt = softplusf(dtr);
    float xv = xsb[row*DD + d];
    float u = dt*xv;
    #pragma unroll
    for (int n=0;n<NN;n++){
      float dA = __expf(dt*A[n]);
      P[n] *= dA;
      S[n] = S[n]*dA + u*xdr[RR+n];
    }
  }
  int off = ((bk*DD+d)*NCH + c)*NN;
  #pragma unroll
  for (int n=0;n<NN;n++){ Pb[off+n]=P[n]; Sb[off+n]=S[n]; }
}

// 10: inter-chunk scan; writes Hin in-place over Pb
__global__ void k_scanmid(float* Pb, const float* Sb){
  int idx = blockIdx.x*256 + threadIdx.x;
  if (idx >= BB*KK*DD*NN) return;
  int n = idx%NN, bkd = idx/NN;
  float h = 0.f;
  for (int c=0;c<NCH;c++){
    int o = (bkd*NCH + c)*NN + n;
    float p = Pb[o], s = Sb[o];
    Pb[o] = h;
    h = p*h + s;
  }
}

// 11: scan pass2 — replay with carry-in, atomic-accumulate into Y (b,l,d)
__global__ void k_scan2(const float* xs, const float* xd, const float* dtw, const float* dtb,
                        const float* Alog, const float* Hin, const float* Ds, float* Y){
  int idx = blockIdx.x*256 + threadIdx.x;
  if (idx >= BB*KK*NCH*DD) return;
  int d = idx%DD, c = (idx/DD)%NCH, bk = idx/(DD*NCH);
  int k = bk%KK, b = bk/KK;
  int kd = k*DD+d;
  float w6[RR];
  #pragma unroll
  for (int r=0;r<RR;r++) w6[r] = dtw[kd*RR+r];
  float bias = dtb[kd];
  float A[NN], h[NN];
  int hoff = ((bk*DD+d)*NCH + c)*NN;
  #pragma unroll
  for (int n=0;n<NN;n++){ A[n] = -expf(Alog[kd*NN+n]); h[n] = Hin[hoff+n]; }
  float Dv = Ds[kd];
  int k01 = k&1;
  const float* xsb = xs + (b*2+k01)*LL*DD;
  const float* xdb = xd + bk*LL*38;
  float* yb = Y + b*LL*DD;
  bool rev = (k>=2);
  for (int j=0;j<CLEN;j++){
    int t = c*CLEN + j;
    int row = rev ? (LL-1-t) : t;
    const float* xdr = xdb + t*38;
    float dtr = bias;
    #pragma unroll
    for (int r=0;r<RR;r++) dtr += w6[r]*xdr[r];
    float dt = softplusf(dtr);
    float xv = xsb[row*DD + d];
    float u = dt*xv;
    float y = 0.f;
    #pragma unroll
    for (int n=0;n<NN;n++){
      float dA = __expf(dt*A[n]);
      h[n] = h[n]*dA + u*xdr[RR+n];
      y += h[n]*xdr[RR+NN+n];
    }
    int p = xpos(k, t);
    atomicAdd(&yb[p*DD + d], y + Dv*xv);
  }
}

// 13: layernorm over d (wave per row), * onorm, * z1 -> YZ (b,l,d)
__global__ void k_ln(const float* Y, const float* og, const float* ob, const float* z1, float* yz){
  int r = blockIdx.x*4 + (threadIdx.x >> 6);   // row = b*LL + l
  int lane = threadIdx.x & 63;
  int b = r/LL, l = r%LL;
  const float* yp = Y + r*DD;
  float v0 = yp[lane], v1 = yp[lane+64], v2 = yp[lane+128];
  float s = v0+v1+v2;
  #pragma unroll
  for (int off=32; off>0; off>>=1) s += __shfl_xor(s, off, 64);
  float m = s*(1.0f/DD);
  float t0=v0-m, t1=v1-m, t2=v2-m;
  float vv = t0*t0+t1*t1+t2*t2;
  #pragma unroll
  for (int off=32; off>0; off>>=1) vv += __shfl_xor(vv, off, 64);
  float rs = rsqrtf(vv*(1.0f/DD) + 1e-5f);
  #pragma unroll
  for (int i=0;i<3;i++){
    int d = lane + 64*i;
    float t = (i==0?t0:(i==1?t1:t2));
    float o = (t*rs*og[d] + ob[d]) * z1[(b*DD+d)*LL + l];
    yz[r*DD + d] = o;
  }
}

// 14: x2 = res1 + conv1x1(yz(b,l,d), out_proj_w); xb = bn_n2(x2)  [4-way tile]
__global__ void k_outproj(const float* yz, const float* w, const float* res, const float* g, const float* b_,
                          float* x2, float* xb){
  int idx = blockIdx.x*256 + threadIdx.x;
  if (idx >= BB*24*LL) return;
  int l = idx%LL, og = (idx/LL)%24, b = idx/(LL*24);
  const float* ip = yz + (b*LL+l)*DD;
  float acc[4] = {0.f,0.f,0.f,0.f};
  for (int d=0;d<DD;d++){
    float yv = ip[d];
    #pragma unroll
    for (int j=0;j<4;j++) acc[j] += w[(og+24*j)*DD+d]*yv;
  }
  #pragma unroll
  for (int j=0;j<4;j++){
    int o = og+24*j;
    float v = res[(b*CC+o)*LL+l] + acc[j];
    x2[(b*CC+o)*LL+l] = v;
    xb[(b*CC+o)*LL+l] = v*(g[o]*BNS) + b_[o];
  }
}

// 15: spatial mean per (b,c) — block per row
__global__ void k_gmean(const float* xb, float* gv){
  __shared__ float sm[4];
  int bc = blockIdx.x;
  int tid = threadIdx.x;
  const float* p = xb + bc*LL;
  float s = 0.f;
  for (int l=tid; l<LL; l+=256) s += p[l];
  #pragma unroll
  for (int off=32; off>0; off>>=1) s += __shfl_xor(s, off, 64);
  if ((tid&63)==0) sm[tid>>6] = s;
  __syncthreads();
  if (tid==0) gv[bc] = (sm[0]+sm[1]+sm[2]+sm[3])*(1.0f/LL);
}

// 16: router
__global__ void k_router(const float* gv, const float* rw, const float* rb, float* wm){
  int b = threadIdx.x;
  if (b >= BB) return;
  float lg[EE];
  for (int e=0;e<EE;e++){
    float a = rb[e];
    for (int c=0;c<CC;c++) a += gv[b*CC+c]*rw[e*CC+c];
    lg[e] = a*0.5f;
  }
  float mx = lg[0];
  for (int e=1;e<EE;e++) mx = fmaxf(mx, lg[e]);
  float p[EE], s = 0.f;
  for (int e=0;e<EE;e++){ p[e] = __expf(lg[e]-mx); s += p[e]; }
  for (int e=0;e<EE;e++) p[e] /= s;
  int i1 = 0;
  for (int e=1;e<EE;e++) if (p[e] > p[i1]) i1 = e;
  int i2 = -1;
  for (int e=0;e<EE;e++){ if (e==i1) continue; if (i2<0 || p[e]>p[i2]) i2 = e; }
  float tot = p[i1]+p[i2];
  for (int e=0;e<EE;e++) wm[b*EE+e] = 0.f;
  wm[b*EE+i1] = p[i1]/tot;
  wm[b*EE+i2] = p[i2]/tot;
}

// 17: per-expert dwconv+gelu (skip unselected)
__global__ void k_moedw(const float* xb, const float* dw, const float* db, const float* wm, float* he){
  int idx = blockIdx.x*256 + threadIdx.x;
  if (idx >= EE*BB*CC*LL) return;
  int l = idx%LL, c = (idx/LL)%CC, b = (idx/(LL*CC))%BB, e = idx/(LL*CC*BB);
  if (wm[b*EE+e] == 0.f) return;
  int y = l/40, x0 = l%40;
  const float* ip = xb + (b*CC+c)*LL;
  float acc = 0.f;
  #pragma unroll
  for (int ky=0;ky<3;ky++){
    int yy = y+ky-1; if (yy<0||yy>=40) continue;
    #pragma unroll
    for (int kx=0;kx<3;kx++){
      int xx = x0+kx-1; if (xx<0||xx>=40) continue;
      acc += dw[(e*CC+c)*9+ky*3+kx] * ip[yy*40+xx];
    }
  }
  he[((e*BB+b)*CC+c)*LL+l] = geluf(acc + db[e*CC+c]);
}

// 18: out = x2 + sum_e wm*(conv1x1(he_e)+pb_e)  [4-way tile], dtype-branch store
__global__ void k_final(const float* he, const float* pw, const float* pb, const float* wm,
                        const float* x2, void* out, const void* dsraw){
  bool f32 = (((const unsigned*)dsraw)[0] == 0x3F800000u);
  int idx = blockIdx.x*256 + threadIdx.x;
  if (idx >= BB*24*LL) return;
  int l = idx%LL, og = (idx/LL)%24, b = idx/(LL*24);
  float acc[4];
  #pragma unroll
  for (int j=0;j<4;j++) acc[j] = x2[(b*CC+og+24*j)*LL+l];
  for (int e=0;e<EE;e++){
    float wv = wm[b*EE+e];
    if (wv == 0.f) continue;
    const float* hp = he + (e*BB+b)*CC*LL + l;
    float s[4];
    #pragma unroll
    for (int j=0;j<4;j++) s[j] = pb[e*CC+og+24*j];
    for (int c=0;c<CC;c++){
      float hv = hp[c*LL];
      #pragma unroll
      for (int j=0;j<4;j++) s[j] += pw[(e*CC+og+24*j)*CC+c]*hv;
    }
    #pragma unroll
    for (int j=0;j<4;j++) acc[j] += wv*s[j];
  }
  #pragma unroll
  for (int j=0;j<4;j++){
    int o = (b*CC+og+24*j)*LL+l;
    if (f32) ((float*)out)[o] = acc[j];
    else     ((bf16*)out)[o] = __float2bfloat16(acc[j]);
  }
}

extern "C" void kernel_launch(void* const* d_in, const int* in_sizes, int n_in,
                              void* d_out, int out_size, void* d_ws, size_t ws_size,
                              hipStream_t stream) {
  static const int cum[34] = {
    0, 614400, 623616, 623712, 623808, 624672, 624768, 624864, 624960,
    634176, 634272, 643488, 643584, 643680, 643776, 680640, 682368, 682560,
    711744, 716352, 717120, 729408, 730176, 730368, 730560, 748992, 749088,
    749184, 749568, 749572, 753028, 753412, 790276, 790660
  };
  float* ws = (float*)d_ws;
  const float* cv[33];
  P33 ps;
  for (int i=0;i<33;i++){ ps.p[i] = d_in[i]; cv[i] = ws + cum[i]; }

  const float* c_x    = cv[0];
  const float* c_pw   = cv[1];
  const float* c_bn0g = cv[2];
  const float* c_bn0b = cv[3];
  const float* c_f1w  = cv[4];
  const float* c_f1b  = cv[5];
  const float* c_lbg  = cv[6];
  const float* c_lbb  = cv[7];
  const float* c_f2w  = cv[8];
  const float* c_f2b  = cv[9];
  const float* c_f3w  = cv[10];
  const float* c_f3b  = cv[11];
  const float* c_n1g  = cv[12];
  const float* c_n1b  = cv[13];
  const float* c_ipw  = cv[14];
  const float* c_cw   = cv[15];
  const float* c_cb   = cv[16];
  const float* c_xpw  = cv[17];
  const float* c_dtw  = cv[18];
  const float* c_dtb  = cv[19];
  const float* c_al   = cv[20];
  const float* c_ds   = cv[21];
  const float* c_ong  = cv[22];
  const float* c_onb  = cv[23];
  const float* c_opw  = cv[24];
  const float* c_n2g  = cv[25];
  const float* c_n2b  = cv[26];
  const float* c_rw   = cv[27];
  const float* c_rb   = cv[28];
  const float* c_mdw  = cv[29];
  const float* c_mdb  = cv[30];
  const float* c_mpw  = cv[31];
  const float* c_mpb  = cv[32];

  // arena (floats), total 13,682,944 = 54.7 MB
  float* R   = ws +   790784;  // 614400   k_proj -> k_outproj
  float* T1  = ws +  1405184;  // slot B: T1 -> X1 -> X2
  float* X1  = T1;
  float* X2  = T1;
  float* T2  = ws +  2019584;  // slot C: T2 -> XB
  float* XB  = T2;
  float* XXP = ws +  2633984;  // slot D: XXP -> Y (1,228,800)
  float* Y   = XXP;
  float* Z1  = ws +  3862784;  // 1,228,800, live to k_ln
  float* XX  = ws +  5091584;  // slot F: XX -> YZ (1,228,800)
  float* YZ  = XX;
  float* XS  = ws +  6320384;  // slot G: XS (2,457,600) -> HE
  float* HE  = XS;
  float* XD  = ws +  8777984;  // slot H: XD (972,800) -> GV/WM
  float* GV  = XD;
  float* WM  = XD + 384;
  float* PB  = ws +  9750784;  // 1,966,080 (Hin in-place)
  float* SB  = ws + 11716864;  // 1,966,080

  const int T = 256;
  k_convert  <<<(NTOT+T-1)/T, T, 0, stream>>>(ps, ws);
  k_proj     <<<(BB*24*LL+T-1)/T, T, 0, stream>>>(c_x, c_pw, c_bn0g, c_bn0b, R);
  k_dwbn     <<<(BB*CC*LL+T-1)/T, T, 0, stream>>>(R, c_f1w, c_f1b, c_lbg, c_lbb, T1);
  k_fc_gelu  <<<(BB*24*LL+T-1)/T, T, 0, stream>>>(T1, c_f2w, c_f2b, T2);
  k_fc_res_bn<<<(BB*24*LL+T-1)/T, T, 0, stream>>>(T2, c_f3w, c_f3b, R, c_n1g, c_n1b, X1);
  k_inproj   <<<(BB*96*LL+T-1)/T, T, 0, stream>>>(X1, c_ipw, XXP, Z1);
  k_ssconv   <<<(BB*DD*LL+T-1)/T, T, 0, stream>>>(XXP, c_cw, c_cb, XX);
  k_xs       <<<1200, T, 0, stream>>>(XX, XS);
  hipMemsetAsync(Y, 0, (size_t)BB*DD*LL*sizeof(float), stream);   // Y aliases XXP (dead)
  k_xdbl     <<<(BB*KK*LL*38+T-1)/T, T, 0, stream>>>(XS, c_xpw, XD);
  k_scan1    <<<(BB*KK*NCH*DD+T-1)/T, T, 0, stream>>>(XS, XD, c_dtw, c_dtb, c_al, PB, SB);
  k_scanmid  <<<(BB*KK*DD*NN+T-1)/T, T, 0, stream>>>(PB, SB);
  k_scan2    <<<(BB*KK*NCH*DD+T-1)/T, T, 0, stream>>>(XS, XD, c_dtw, c_dtb, c_al, PB, c_ds, Y);
  k_ln       <<<1600, T, 0, stream>>>(Y, c_ong, c_onb, Z1, YZ);
  k_outproj  <<<(BB*24*LL+T-1)/T, T, 0, stream>>>(YZ, c_opw, R, c_n2g, c_n2b, X2, XB);
  k_gmean    <<<BB*CC, T, 0, stream>>>(XB, GV);
  k_router   <<<1, 64, 0, stream>>>(GV, c_rw, c_rb, WM);
  k_moedw    <<<(EE*BB*CC*LL+T-1)/T, T, 0, stream>>>(XB, c_mdw, c_mdb, WM, HE);
  k_final    <<<(BB*24*LL+T-1)/T, T, 0, stream>>>(HE, c_mpw, c_mpb, WM, X2, d_out, d_in[21]);
}

// Round 4
// 533.946 us; speedup vs baseline: 2.0638x; 1.0888x over previous
//
#include <hip/hip_runtime.h>
#include <hip/hip_bf16.h>
#include <math.h>

#define BB 4
#define CC 96
#define LL 1600
#define DD 192
#define KK 4
#define RR 6
#define NN 16
#define EE 4
#define NCH 40
#define CLEN 40

typedef __hip_bfloat16 bf16;

__device__ __forceinline__ float geluf(float x){ return 0.5f*x*(1.0f+erff(x*0.70710678118654752440f)); }
__device__ __forceinline__ float softplusf(float x){ return (x>20.0f)? x : log1pf(__expf(x)); }
#define BNS rsqrtf(1.0f + 1e-5f)

// hw position for scan-direction k at scan index t
__device__ __forceinline__ int xpos(int k, int l){
  if (k==0) return l;
  if (k==2) return LL-1-l;
  int t = (k==1)? l : (LL-1-l);
  return (t%40)*40 + t/40;   // H==W==40 transpose map (involution)
}

// ---- input conversion: everything -> fp32 in workspace ----
struct P33 { const void* p[33]; };
#define NTOT 790660
__device__ const int g_cum[34] = {
  0, 614400, 623616, 623712, 623808, 624672, 624768, 624864, 624960,
  634176, 634272, 643488, 643584, 643680, 643776, 680640, 682368, 682560,
  711744, 716352, 717120, 729408, 730176, 730368, 730560, 748992, 749088,
  749184, 749568, 749572, 753028, 753412, 790276, 790660
};

__global__ void k_convert(P33 ps, float* cv){
  // Ds is ones: fp32 -> first dword 0x3F800000 ; bf16 -> 0x3F803F80
  bool f32 = (((const unsigned*)ps.p[21])[0] == 0x3F800000u);
  int idx = blockIdx.x*256 + threadIdx.x;
  if (idx >= NTOT) return;
  int lo=0, hi=33;
  while (lo+1<hi){ int mid=(lo+hi)>>1; if (idx >= g_cum[mid]) lo=mid; else hi=mid; }
  int local = idx - g_cum[lo];
  float v = f32 ? ((const float*)ps.p[lo])[local]
                : __bfloat162float(((const bf16*)ps.p[lo])[local]);
  cv[idx] = v;
}

// 1: x = silu(bn0(conv1x1(x, proj_w)))  [4-way o-tile]
__global__ void k_proj(const float* x, const float* w, const float* g, const float* b_, float* out){
  int idx = blockIdx.x*256 + threadIdx.x;
  if (idx >= BB*24*LL) return;
  int l = idx%LL, og = (idx/LL)%24, b = idx/(LL*24);
  const float* xp = x + b*CC*LL + l;
  float acc[4] = {0.f,0.f,0.f,0.f};
  for (int c=0;c<CC;c++){
    float xv = xp[c*LL];
    #pragma unroll
    for (int j=0;j<4;j++) acc[j] += w[(og+24*j)*CC+c]*xv;
  }
  #pragma unroll
  for (int j=0;j<4;j++){
    int o = og+24*j;
    float v = acc[j]*(g[o]*BNS) + b_[o];
    out[(b*CC+o)*LL+l] = v/(1.0f+__expf(-v));
  }
}

// 2: h = bn(dwconv3(R, fc1_w, fc1_b))
__global__ void k_dwbn(const float* in, const float* w, const float* bias, const float* g, const float* b_, float* out){
  int idx = blockIdx.x*256 + threadIdx.x;
  if (idx >= BB*CC*LL) return;
  int l = idx%LL, c = (idx/LL)%CC, b = idx/(LL*CC);
  int y = l/40, x0 = l%40;
  const float* ip = in + (b*CC+c)*LL;
  float acc = 0.f;
  #pragma unroll
  for (int ky=0;ky<3;ky++){
    int yy = y+ky-1; if (yy<0||yy>=40) continue;
    #pragma unroll
    for (int kx=0;kx<3;kx++){
      int xx = x0+kx-1; if (xx<0||xx>=40) continue;
      acc += w[c*9+ky*3+kx] * ip[yy*40+xx];
    }
  }
  acc += bias[c];
  out[idx] = acc*(g[c]*BNS) + b_[c];
}

// 3: gelu(conv1x1 + bias)  [4-way o-tile]
__global__ void k_fc_gelu(const float* in, const float* w, const float* bias, float* out){
  int idx = blockIdx.x*256 + threadIdx.x;
  if (idx >= BB*24*LL) return;
  int l = idx%LL, og = (idx/LL)%24, b = idx/(LL*24);
  const float* ip = in + b*CC*LL + l;
  float acc[4];
  #pragma unroll
  for (int j=0;j<4;j++) acc[j] = bias[og+24*j];
  for (int c=0;c<CC;c++){
    float xv = ip[c*LL];
    #pragma unroll
    for (int j=0;j<4;j++) acc[j] += w[(og+24*j)*CC+c]*xv;
  }
  #pragma unroll
  for (int j=0;j<4;j++) out[(b*CC+og+24*j)*LL+l] = geluf(acc[j]);
}

// 4: X1 = bn_n1( res + conv1x1(in) + bias )  [4-way o-tile]
__global__ void k_fc_res_bn(const float* in, const float* w, const float* bias, const float* res,
                            const float* g, const float* b_, float* out){
  int idx = blockIdx.x*256 + threadIdx.x;
  if (idx >= BB*24*LL) return;
  int l = idx%LL, og = (idx/LL)%24, b = idx/(LL*24);
  const float* ip = in + b*CC*LL + l;
  float acc[4];
  #pragma unroll
  for (int j=0;j<4;j++) acc[j] = bias[og+24*j];
  for (int c=0;c<CC;c++){
    float xv = ip[c*LL];
    #pragma unroll
    for (int j=0;j<4;j++) acc[j] += w[(og+24*j)*CC+c]*xv;
  }
  #pragma unroll
  for (int j=0;j<4;j++){
    int o = og+24*j;
    float v = acc[j] + res[(b*CC+o)*LL+l];
    out[(b*CC+o)*LL+l] = v*(g[o]*BNS) + b_[o];
  }
}

// 5: xz = conv1x1(X1, in_proj_w); oc<192 -> xxp, else z1=gelu  [4-way tile]
__global__ void k_inproj(const float* in, const float* w, float* xxp, float* z1){
  int idx = blockIdx.x*256 + threadIdx.x;
  if (idx >= BB*96*LL) return;
  int l = idx%LL, og = (idx/LL)%96, b = idx/(LL*96);
  const float* ip = in + b*CC*LL + l;
  float acc[4] = {0.f,0.f,0.f,0.f};
  for (int c=0;c<CC;c++){
    float xv = ip[c*LL];
    #pragma unroll
    for (int j=0;j<4;j++) acc[j] += w[(og+96*j)*CC+c]*xv;
  }
  xxp[(b*DD+og)*LL+l]      = acc[0];
  xxp[(b*DD+og+96)*LL+l]   = acc[1];
  z1[(b*DD+og)*LL+l]       = geluf(acc[2]);
  z1[(b*DD+og+96)*LL+l]    = geluf(acc[3]);
}

// 6: xx = gelu(dwconv3(xx_pre, conv_w, conv_b))
__global__ void k_ssconv(const float* in, const float* w, const float* bias, float* out){
  int idx = blockIdx.x*256 + threadIdx.x;
  if (idx >= BB*DD*LL) return;
  int l = idx%LL, d = (idx/LL)%DD, b = idx/(LL*DD);
  int y = l/40, x0 = l%40;
  const float* ip = in + (b*DD+d)*LL;
  float acc = 0.f;
  #pragma unroll
  for (int ky=0;ky<3;ky++){
    int yy = y+ky-1; if (yy<0||yy>=40) continue;
    #pragma unroll
    for (int kx=0;kx<3;kx++){
      int xx = x0+kx-1; if (xx<0||xx>=40) continue;
      acc += w[d*9+ky*3+kx] * ip[yy*40+xx];
    }
  }
  out[idx] = geluf(acc + bias[d]);
}

// 6b: LDS-tiled transpose -> XS (b,k01,l,d); k01=0 rows = l, k01=1 rows = transpose(l)
__global__ void k_xs(const float* xx, float* xs){
  __shared__ float t[32][33];
  int bid = blockIdx.x;
  int lt = bid % 50, dt = (bid/50)%6, b = bid/300;
  int l0 = lt*32, d0 = dt*32;
  int tx = threadIdx.x & 31, ty = threadIdx.x >> 5;
  #pragma unroll
  for (int j=0;j<4;j++){
    int dd = ty + 8*j;
    t[dd][tx] = xx[(b*DD + d0+dd)*LL + l0 + tx];
  }
  __syncthreads();
  #pragma unroll
  for (int j=0;j<4;j++){
    int ll = ty + 8*j;
    int l = l0 + ll;
    float v = t[tx][ll];
    int lw = (l%40)*40 + l/40;
    xs[((b*2+0)*LL + l )*DD + d0 + tx] = v;
    xs[((b*2+1)*LL + lw)*DD + d0 + tx] = v;
  }
}

// 6c: spatial transpose keeping d-major: XW1[b][d][tw] = XX[b][d][(tw%40)*40+tw/40]
__global__ void k_xw(const float* xx, float* xw1){
  __shared__ float sm[40*41];
  int bd = blockIdx.x;
  const float* ip = xx + bd*LL;
  float* op = xw1 + bd*LL;
  for (int i=threadIdx.x; i<LL; i+=256){
    sm[(i/40)*41 + (i%40)] = ip[i];
  }
  __syncthreads();
  for (int i=threadIdx.x; i<LL; i+=256){
    op[i] = sm[(i%40)*41 + (i/40)];   // stride 41: conflict-free
  }
}

// 7: xd (bk,38,L): out[bk,c,l] = sum_d w[k,c,d] * src[b,d,row]; lanes over l (coalesced)
__global__ void k_xdbl(const float* xx, const float* xw1, const float* w, float* xd){
  int idx = blockIdx.x*256 + threadIdx.x;
  if (idx >= BB*KK*10*LL) return;
  int l = idx%LL, cq = (idx/LL)%10, bk = idx/(LL*10);
  int k = bk%KK, b = bk/KK;
  const float* base = ((k&1)? xw1 : xx) + b*DD*LL;
  int row = (k<2)? l : (LL-1-l);
  int jmax = (cq < 8)? 4 : 3;        // c = cq+10j < 38
  const float* w0 = w + (k*38+cq)*DD;
  float acc[4] = {0.f,0.f,0.f,0.f};
  for (int d=0;d<DD;d++){
    float xv = base[d*LL + row];
    #pragma unroll
    for (int j=0;j<4;j++) acc[j] += w0[j*10*DD + d]*xv;   // reads ok: j<jmax used only
  }
  float* out = xd + bk*38*LL;
  for (int j=0;j<jmax;j++) out[(cq+10*j)*LL + l] = acc[j];
}

// 9: scan pass1 — per (b,k,chunk,d): P = prod dA, S = zero-init chunk-end state
__global__ void k_scan1(const float* xs, const float* xd, const float* dtw, const float* dtb,
                        const float* Alog, float* Pb, float* Sb){
  int idx = blockIdx.x*256 + threadIdx.x;
  if (idx >= BB*KK*NCH*DD) return;
  int d = idx%DD, c = (idx/DD)%NCH, bk = idx/(DD*NCH);
  int k = bk%KK, b = bk/KK;
  int kd = k*DD+d;
  float w6[RR];
  #pragma unroll
  for (int r=0;r<RR;r++) w6[r] = dtw[kd*RR+r];
  float bias = dtb[kd];
  float A[NN], P[NN], S[NN];
  #pragma unroll
  for (int n=0;n<NN;n++){ A[n] = -expf(Alog[kd*NN+n]); P[n]=1.f; S[n]=0.f; }
  int k01 = k&1;
  const float* xsb = xs + (b*2+k01)*LL*DD;
  const float* xdb = xd + bk*38*LL;
  bool rev = (k>=2);
  for (int j=0;j<CLEN;j++){
    int t = c*CLEN + j;
    int row = rev ? (LL-1-t) : t;
    float dtr = bias;
    #pragma unroll
    for (int r=0;r<RR;r++) dtr += w6[r]*xdb[r*LL + t];
    float dt = softplusf(dtr);
    float xv = xsb[row*DD + d];
    float u = dt*xv;
    #pragma unroll
    for (int n=0;n<NN;n++){
      float dA = __expf(dt*A[n]);
      P[n] *= dA;
      S[n] = S[n]*dA + u*xdb[(RR+n)*LL + t];
    }
  }
  int off = ((bk*DD+d)*NCH + c)*NN;
  #pragma unroll
  for (int n=0;n<NN;n++){ Pb[off+n]=P[n]; Sb[off+n]=S[n]; }
}

// 10: inter-chunk scan; writes Hin in-place over Pb
__global__ void k_scanmid(float* Pb, const float* Sb){
  int idx = blockIdx.x*256 + threadIdx.x;
  if (idx >= BB*KK*DD*NN) return;
  int n = idx%NN, bkd = idx/NN;
  float h = 0.f;
  for (int c=0;c<NCH;c++){
    int o = (bkd*NCH + c)*NN + n;
    float p = Pb[o], s = Sb[o];
    Pb[o] = h;
    h = p*h + s;
  }
}

// 11: scan pass2 — replay with carry-in, atomic-accumulate into Y (b,l,d)
__global__ void k_scan2(const float* xs, const float* xd, const float* dtw, const float* dtb,
                        const float* Alog, const float* Hin, const float* Ds, float* Y){
  int idx = blockIdx.x*256 + threadIdx.x;
  if (idx >= BB*KK*NCH*DD) return;
  int d = idx%DD, c = (idx/DD)%NCH, bk = idx/(DD*NCH);
  int k = bk%KK, b = bk/KK;
  int kd = k*DD+d;
  float w6[RR];
  #pragma unroll
  for (int r=0;r<RR;r++) w6[r] = dtw[kd*RR+r];
  float bias = dtb[kd];
  float A[NN], h[NN];
  int hoff = ((bk*DD+d)*NCH + c)*NN;
  #pragma unroll
  for (int n=0;n<NN;n++){ A[n] = -expf(Alog[kd*NN+n]); h[n] = Hin[hoff+n]; }
  float Dv = Ds[kd];
  int k01 = k&1;
  const float* xsb = xs + (b*2+k01)*LL*DD;
  const float* xdb = xd + bk*38*LL;
  float* yb = Y + b*LL*DD;
  bool rev = (k>=2);
  for (int j=0;j<CLEN;j++){
    int t = c*CLEN + j;
    int row = rev ? (LL-1-t) : t;
    float dtr = bias;
    #pragma unroll
    for (int r=0;r<RR;r++) dtr += w6[r]*xdb[r*LL + t];
    float dt = softplusf(dtr);
    float xv = xsb[row*DD + d];
    float u = dt*xv;
    float y = 0.f;
    #pragma unroll
    for (int n=0;n<NN;n++){
      float dA = __expf(dt*A[n]);
      h[n] = h[n]*dA + u*xdb[(RR+n)*LL + t];
      y += h[n]*xdb[(RR+NN+n)*LL + t];
    }
    int p = xpos(k, t);
    atomicAdd(&yb[p*DD + d], y + Dv*xv);
  }
}

// 13: layernorm over d (wave per row), * onorm, * z1 -> YZ (b,l,d)
__global__ void k_ln(const float* Y, const float* og, const float* ob, const float* z1, float* yz){
  int r = blockIdx.x*4 + (threadIdx.x >> 6);
  int lane = threadIdx.x & 63;
  int b = r/LL, l = r%LL;
  const float* yp = Y + r*DD;
  float v0 = yp[lane], v1 = yp[lane+64], v2 = yp[lane+128];
  float s = v0+v1+v2;
  #pragma unroll
  for (int off=32; off>0; off>>=1) s += __shfl_xor(s, off, 64);
  float m = s*(1.0f/DD);
  float t0=v0-m, t1=v1-m, t2=v2-m;
  float vv = t0*t0+t1*t1+t2*t2;
  #pragma unroll
  for (int off=32; off>0; off>>=1) vv += __shfl_xor(vv, off, 64);
  float rs = rsqrtf(vv*(1.0f/DD) + 1e-5f);
  #pragma unroll
  for (int i=0;i<3;i++){
    int d = lane + 64*i;
    float t = (i==0?t0:(i==1?t1:t2));
    float o = (t*rs*og[d] + ob[d]) * z1[(b*DD+d)*LL + l];
    yz[r*DD + d] = o;
  }
}

// 14: x2 = res1 + conv1x1(yz(b,l,d), out_proj_w); xb = bn_n2(x2)  [4-way tile]
__global__ void k_outproj(const float* yz, const float* w, const float* res, const float* g, const float* b_,
                          float* x2, float* xb){
  int idx = blockIdx.x*256 + threadIdx.x;
  if (idx >= BB*24*LL) return;
  int l = idx%LL, og = (idx/LL)%24, b = idx/(LL*24);
  const float* ip = yz + (b*LL+l)*DD;
  float acc[4] = {0.f,0.f,0.f,0.f};
  for (int d=0;d<DD;d++){
    float yv = ip[d];
    #pragma unroll
    for (int j=0;j<4;j++) acc[j] += w[(og+24*j)*DD+d]*yv;
  }
  #pragma unroll
  for (int j=0;j<4;j++){
    int o = og+24*j;
    float v = res[(b*CC+o)*LL+l] + acc[j];
    x2[(b*CC+o)*LL+l] = v;
    xb[(b*CC+o)*LL+l] = v*(g[o]*BNS) + b_[o];
  }
}

// 15: spatial mean per (b,c) — block per row
__global__ void k_gmean(const float* xb, float* gv){
  __shared__ float sm[4];
  int bc = blockIdx.x;
  int tid = threadIdx.x;
  const float* p = xb + bc*LL;
  float s = 0.f;
  for (int l=tid; l<LL; l+=256) s += p[l];
  #pragma unroll
  for (int off=32; off>0; off>>=1) s += __shfl_xor(s, off, 64);
  if ((tid&63)==0) sm[tid>>6] = s;
  __syncthreads();
  if (tid==0) gv[bc] = (sm[0]+sm[1]+sm[2]+sm[3])*(1.0f/LL);
}

// 16: router
__global__ void k_router(const float* gv, const float* rw, const float* rb, float* wm){
  int b = threadIdx.x;
  if (b >= BB) return;
  float lg[EE];
  for (int e=0;e<EE;e++){
    float a = rb[e];
    for (int c=0;c<CC;c++) a += gv[b*CC+c]*rw[e*CC+c];
    lg[e] = a*0.5f;
  }
  float mx = lg[0];
  for (int e=1;e<EE;e++) mx = fmaxf(mx, lg[e]);
  float p[EE], s = 0.f;
  for (int e=0;e<EE;e++){ p[e] = __expf(lg[e]-mx); s += p[e]; }
  for (int e=0;e<EE;e++) p[e] /= s;
  int i1 = 0;
  for (int e=1;e<EE;e++) if (p[e] > p[i1]) i1 = e;
  int i2 = -1;
  for (int e=0;e<EE;e++){ if (e==i1) continue; if (i2<0 || p[e]>p[i2]) i2 = e; }
  float tot = p[i1]+p[i2];
  for (int e=0;e<EE;e++) wm[b*EE+e] = 0.f;
  wm[b*EE+i1] = p[i1]/tot;
  wm[b*EE+i2] = p[i2]/tot;
}

// 17: per-expert dwconv+gelu (skip unselected)
__global__ void k_moedw(const float* xb, const float* dw, const float* db, const float* wm, float* he){
  int idx = blockIdx.x*256 + threadIdx.x;
  if (idx >= EE*BB*CC*LL) return;
  int l = idx%LL, c = (idx/LL)%CC, b = (idx/(LL*CC))%BB, e = idx/(LL*CC*BB);
  if (wm[b*EE+e] == 0.f) return;
  int y = l/40, x0 = l%40;
  const float* ip = xb + (b*CC+c)*LL;
  float acc = 0.f;
  #pragma unroll
  for (int ky=0;ky<3;ky++){
    int yy = y+ky-1; if (yy<0||yy>=40) continue;
    #pragma unroll
    for (int kx=0;kx<3;kx++){
      int xx = x0+kx-1; if (xx<0||xx>=40) continue;
      acc += dw[(e*CC+c)*9+ky*3+kx] * ip[yy*40+xx];
    }
  }
  he[((e*BB+b)*CC+c)*LL+l] = geluf(acc + db[e*CC+c]);
}

// 18: out = x2 + sum_e wm*(conv1x1(he_e)+pb_e)  [4-way tile], dtype-branch store
__global__ void k_final(const float* he, const float* pw, const float* pb, const float* wm,
                        const float* x2, void* out, const void* dsraw){
  bool f32 = (((const unsigned*)dsraw)[0] == 0x3F800000u);
  int idx = blockIdx.x*256 + threadIdx.x;
  if (idx >= BB*24*LL) return;
  int l = idx%LL, og = (idx/LL)%24, b = idx/(LL*24);
  float acc[4];
  #pragma unroll
  for (int j=0;j<4;j++) acc[j] = x2[(b*CC+og+24*j)*LL+l];
  for (int e=0;e<EE;e++){
    float wv = wm[b*EE+e];
    if (wv == 0.f) continue;
    const float* hp = he + (e*BB+b)*CC*LL + l;
    float s[4];
    #pragma unroll
    for (int j=0;j<4;j++) s[j] = pb[e*CC+og+24*j];
    for (int c=0;c<CC;c++){
      float hv = hp[c*LL];
      #pragma unroll
      for (int j=0;j<4;j++) s[j] += pw[(e*CC+og+24*j)*CC+c]*hv;
    }
    #pragma unroll
    for (int j=0;j<4;j++) acc[j] += wv*s[j];
  }
  #pragma unroll
  for (int j=0;j<4;j++){
    int o = (b*CC+og+24*j)*LL+l;
    if (f32) ((float*)out)[o] = acc[j];
    else     ((bf16*)out)[o] = __float2bfloat16(acc[j]);
  }
}

extern "C" void kernel_launch(void* const* d_in, const int* in_sizes, int n_in,
                              void* d_out, int out_size, void* d_ws, size_t ws_size,
                              hipStream_t stream) {
  static const int cum[34] = {
    0, 614400, 623616, 623712, 623808, 624672, 624768, 624864, 624960,
    634176, 634272, 643488, 643584, 643680, 643776, 680640, 682368, 682560,
    711744, 716352, 717120, 729408, 730176, 730368, 730560, 748992, 749088,
    749184, 749568, 749572, 753028, 753412, 790276, 790660
  };
  float* ws = (float*)d_ws;
  const float* cv[33];
  P33 ps;
  for (int i=0;i<33;i++){ ps.p[i] = d_in[i]; cv[i] = ws + cum[i]; }

  const float* c_x    = cv[0];
  const float* c_pw   = cv[1];
  const float* c_bn0g = cv[2];
  const float* c_bn0b = cv[3];
  const float* c_f1w  = cv[4];
  const float* c_f1b  = cv[5];
  const float* c_lbg  = cv[6];
  const float* c_lbb  = cv[7];
  const float* c_f2w  = cv[8];
  const float* c_f2b  = cv[9];
  const float* c_f3w  = cv[10];
  const float* c_f3b  = cv[11];
  const float* c_n1g  = cv[12];
  const float* c_n1b  = cv[13];
  const float* c_ipw  = cv[14];
  const float* c_cw   = cv[15];
  const float* c_cb   = cv[16];
  const float* c_xpw  = cv[17];
  const float* c_dtw  = cv[18];
  const float* c_dtb  = cv[19];
  const float* c_al   = cv[20];
  const float* c_ds   = cv[21];
  const float* c_ong  = cv[22];
  const float* c_onb  = cv[23];
  const float* c_opw  = cv[24];
  const float* c_n2g  = cv[25];
  const float* c_n2b  = cv[26];
  const float* c_rw   = cv[27];
  const float* c_rb   = cv[28];
  const float* c_mdw  = cv[29];
  const float* c_mdb  = cv[30];
  const float* c_mpw  = cv[31];
  const float* c_mpb  = cv[32];

  // arena (floats), total 13,682,944 = 54.7 MB
  float* R   = ws +   790784;  // 614400   k_proj -> k_outproj
  float* T1  = ws +  1405184;  // slot B: T1 -> X1 -> [XW1 window] -> X2
  float* X1  = T1;
  float* X2  = T1;
  float* T2  = ws +  2019584;  // slot C: T2 -> [XW1 window] -> XB
  float* XB  = T2;
  float* XW1 = T1;             // spans B+C (1,228,800), live k_xw -> k_xdbl only
  float* XXP = ws +  2633984;  // slot D: XXP -> Y (1,228,800)
  float* Y   = XXP;
  float* Z1  = ws +  3862784;  // 1,228,800, live to k_ln
  float* XX  = ws +  5091584;  // slot F: XX -> YZ (1,228,800)
  float* YZ  = XX;
  float* XS  = ws +  6320384;  // slot G: XS (2,457,600) -> HE
  float* HE  = XS;
  float* XD  = ws +  8777984;  // slot H: XD (972,800) -> GV/WM
  float* GV  = XD;
  float* WM  = XD + 384;
  float* PB  = ws +  9750784;  // 1,966,080 (Hin in-place)
  float* SB  = ws + 11716864;  // 1,966,080

  const int T = 256;
  k_convert  <<<(NTOT+T-1)/T, T, 0, stream>>>(ps, ws);
  k_proj     <<<(BB*24*LL+T-1)/T, T, 0, stream>>>(c_x, c_pw, c_bn0g, c_bn0b, R);
  k_dwbn     <<<(BB*CC*LL+T-1)/T, T, 0, stream>>>(R, c_f1w, c_f1b, c_lbg, c_lbb, T1);
  k_fc_gelu  <<<(BB*24*LL+T-1)/T, T, 0, stream>>>(T1, c_f2w, c_f2b, T2);
  k_fc_res_bn<<<(BB*24*LL+T-1)/T, T, 0, stream>>>(T2, c_f3w, c_f3b, R, c_n1g, c_n1b, X1);
  k_inproj   <<<(BB*96*LL+T-1)/T, T, 0, stream>>>(X1, c_ipw, XXP, Z1);
  k_ssconv   <<<(BB*DD*LL+T-1)/T, T, 0, stream>>>(XXP, c_cw, c_cb, XX);
  k_xs       <<<1200, T, 0, stream>>>(XX, XS);
  k_xw       <<<BB*DD, T, 0, stream>>>(XX, XW1);
  hipMemsetAsync(Y, 0, (size_t)BB*DD*LL*sizeof(float), stream);   // Y aliases XXP (dead)
  k_xdbl     <<<(BB*KK*10*LL+T-1)/T, T, 0, stream>>>(XX, XW1, c_xpw, XD);
  k_scan1    <<<(BB*KK*NCH*DD+T-1)/T, T, 0, stream>>>(XS, XD, c_dtw, c_dtb, c_al, PB, SB);
  k_scanmid  <<<(BB*KK*DD*NN+T-1)/T, T, 0, stream>>>(PB, SB);
  k_scan2    <<<(BB*KK*NCH*DD+T-1)/T, T, 0, stream>>>(XS, XD, c_dtw, c_dtb, c_al, PB, c_ds, Y);
  k_ln       <<<1600, T, 0, stream>>>(Y, c_ong, c_onb, Z1, YZ);
  k_outproj  <<<(BB*24*LL+T-1)/T, T, 0, stream>>>(YZ, c_opw, R, c_n2g, c_n2b, X2, XB);
  k_gmean    <<<BB*CC, T, 0, stream>>>(XB, GV);
  k_router   <<<1, 64, 0, stream>>>(GV, c_rw, c_rb, WM);
  k_moedw    <<<(EE*BB*CC*LL+T-1)/T, T, 0, stream>>>(XB, c_mdw, c_mdb, WM, HE);
  k_final    <<<(BB*24*LL+T-1)/T, T, 0, stream>>>(HE, c_mpw, c_mpb, WM, X2, d_out, d_in[21]);
}

// Round 5
// 513.664 us; speedup vs baseline: 2.1453x; 1.0395x over previous
//
#include <hip/hip_runtime.h>
#include <hip/hip_bf16.h>
#include <math.h>

#define BB 4
#define CC 96
#define LL 1600
#define DD 192
#define KK 4
#define RR 6
#define NN 16
#define EE 4
#define NCH 40
#define CLEN 40
#define DH 6          // DD/32
#define NG 2          // n-split groups
#define NH 8          // NN/NG

typedef __hip_bfloat16 bf16;

__device__ __forceinline__ float geluf(float x){ return 0.5f*x*(1.0f+erff(x*0.70710678118654752440f)); }
__device__ __forceinline__ float softplusf(float x){ return (x>20.0f)? x : __logf(1.0f+__expf(x)); }
#define BNS rsqrtf(1.0f + 1e-5f)
#define LOG2E 1.44269504088896340736f

// hw position for scan-direction k at scan index t
__device__ __forceinline__ int xpos(int k, int l){
  if (k==0) return l;
  if (k==2) return LL-1-l;
  int t = (k==1)? l : (LL-1-l);
  return (t%40)*40 + t/40;   // H==W==40 transpose map (involution)
}

// ---- input conversion: everything -> fp32 in workspace ----
struct P33 { const void* p[33]; };
#define NTOT 790660
__device__ const int g_cum[34] = {
  0, 614400, 623616, 623712, 623808, 624672, 624768, 624864, 624960,
  634176, 634272, 643488, 643584, 643680, 643776, 680640, 682368, 682560,
  711744, 716352, 717120, 729408, 730176, 730368, 730560, 748992, 749088,
  749184, 749568, 749572, 753028, 753412, 790276, 790660
};

__global__ void k_convert(P33 ps, float* cv){
  // Ds is ones: fp32 -> first dword 0x3F800000 ; bf16 -> 0x3F803F80
  bool f32 = (((const unsigned*)ps.p[21])[0] == 0x3F800000u);
  int idx = blockIdx.x*256 + threadIdx.x;
  if (idx >= NTOT) return;
  int lo=0, hi=33;
  while (lo+1<hi){ int mid=(lo+hi)>>1; if (idx >= g_cum[mid]) lo=mid; else hi=mid; }
  int local = idx - g_cum[lo];
  float v = f32 ? ((const float*)ps.p[lo])[local]
                : __bfloat162float(((const bf16*)ps.p[lo])[local]);
  cv[idx] = v;
}

// 1: x = silu(bn0(conv1x1(x, proj_w)))  [4-way o-tile]
__global__ void k_proj(const float* x, const float* w, const float* g, const float* b_, float* out){
  int idx = blockIdx.x*256 + threadIdx.x;
  if (idx >= BB*24*LL) return;
  int l = idx%LL, og = (idx/LL)%24, b = idx/(LL*24);
  const float* xp = x + b*CC*LL + l;
  float acc[4] = {0.f,0.f,0.f,0.f};
  for (int c=0;c<CC;c++){
    float xv = xp[c*LL];
    #pragma unroll
    for (int j=0;j<4;j++) acc[j] += w[(og+24*j)*CC+c]*xv;
  }
  #pragma unroll
  for (int j=0;j<4;j++){
    int o = og+24*j;
    float v = acc[j]*(g[o]*BNS) + b_[o];
    out[(b*CC+o)*LL+l] = v/(1.0f+__expf(-v));
  }
}

// 2: h = bn(dwconv3(R, fc1_w, fc1_b))
__global__ void k_dwbn(const float* in, const float* w, const float* bias, const float* g, const float* b_, float* out){
  int idx = blockIdx.x*256 + threadIdx.x;
  if (idx >= BB*CC*LL) return;
  int l = idx%LL, c = (idx/LL)%CC, b = idx/(LL*CC);
  int y = l/40, x0 = l%40;
  const float* ip = in + (b*CC+c)*LL;
  float acc = 0.f;
  #pragma unroll
  for (int ky=0;ky<3;ky++){
    int yy = y+ky-1; if (yy<0||yy>=40) continue;
    #pragma unroll
    for (int kx=0;kx<3;kx++){
      int xx = x0+kx-1; if (xx<0||xx>=40) continue;
      acc += w[c*9+ky*3+kx] * ip[yy*40+xx];
    }
  }
  acc += bias[c];
  out[idx] = acc*(g[c]*BNS) + b_[c];
}

// 3: gelu(conv1x1 + bias)  [4-way o-tile]
__global__ void k_fc_gelu(const float* in, const float* w, const float* bias, float* out){
  int idx = blockIdx.x*256 + threadIdx.x;
  if (idx >= BB*24*LL) return;
  int l = idx%LL, og = (idx/LL)%24, b = idx/(LL*24);
  const float* ip = in + b*CC*LL + l;
  float acc[4];
  #pragma unroll
  for (int j=0;j<4;j++) acc[j] = bias[og+24*j];
  for (int c=0;c<CC;c++){
    float xv = ip[c*LL];
    #pragma unroll
    for (int j=0;j<4;j++) acc[j] += w[(og+24*j)*CC+c]*xv;
  }
  #pragma unroll
  for (int j=0;j<4;j++) out[(b*CC+og+24*j)*LL+l] = geluf(acc[j]);
}

// 4: X1 = bn_n1( res + conv1x1(in) + bias )  [4-way o-tile]
__global__ void k_fc_res_bn(const float* in, const float* w, const float* bias, const float* res,
                            const float* g, const float* b_, float* out){
  int idx = blockIdx.x*256 + threadIdx.x;
  if (idx >= BB*24*LL) return;
  int l = idx%LL, og = (idx/LL)%24, b = idx/(LL*24);
  const float* ip = in + b*CC*LL + l;
  float acc[4];
  #pragma unroll
  for (int j=0;j<4;j++) acc[j] = bias[og+24*j];
  for (int c=0;c<CC;c++){
    float xv = ip[c*LL];
    #pragma unroll
    for (int j=0;j<4;j++) acc[j] += w[(og+24*j)*CC+c]*xv;
  }
  #pragma unroll
  for (int j=0;j<4;j++){
    int o = og+24*j;
    float v = acc[j] + res[(b*CC+o)*LL+l];
    out[(b*CC+o)*LL+l] = v*(g[o]*BNS) + b_[o];
  }
}

// 5: xz = conv1x1(X1, in_proj_w); oc<192 -> xxp, else z1=gelu  [4-way tile]
__global__ void k_inproj(const float* in, const float* w, float* xxp, float* z1){
  int idx = blockIdx.x*256 + threadIdx.x;
  if (idx >= BB*96*LL) return;
  int l = idx%LL, og = (idx/LL)%96, b = idx/(LL*96);
  const float* ip = in + b*CC*LL + l;
  float acc[4] = {0.f,0.f,0.f,0.f};
  for (int c=0;c<CC;c++){
    float xv = ip[c*LL];
    #pragma unroll
    for (int j=0;j<4;j++) acc[j] += w[(og+96*j)*CC+c]*xv;
  }
  xxp[(b*DD+og)*LL+l]      = acc[0];
  xxp[(b*DD+og+96)*LL+l]   = acc[1];
  z1[(b*DD+og)*LL+l]       = geluf(acc[2]);
  z1[(b*DD+og+96)*LL+l]    = geluf(acc[3]);
}

// 6: xx = gelu(dwconv3(xx_pre, conv_w, conv_b))
__global__ void k_ssconv(const float* in, const float* w, const float* bias, float* out){
  int idx = blockIdx.x*256 + threadIdx.x;
  if (idx >= BB*DD*LL) return;
  int l = idx%LL, d = (idx/LL)%DD, b = idx/(LL*DD);
  int y = l/40, x0 = l%40;
  const float* ip = in + (b*DD+d)*LL;
  float acc = 0.f;
  #pragma unroll
  for (int ky=0;ky<3;ky++){
    int yy = y+ky-1; if (yy<0||yy>=40) continue;
    #pragma unroll
    for (int kx=0;kx<3;kx++){
      int xx = x0+kx-1; if (xx<0||xx>=40) continue;
      acc += w[d*9+ky*3+kx] * ip[yy*40+xx];
    }
  }
  out[idx] = geluf(acc + bias[d]);
}

// 6b: LDS-tiled transpose -> XS (b,k01,l,d)
__global__ void k_xs(const float* xx, float* xs){
  __shared__ float t[32][33];
  int bid = blockIdx.x;
  int lt = bid % 50, dt = (bid/50)%6, b = bid/300;
  int l0 = lt*32, d0 = dt*32;
  int tx = threadIdx.x & 31, ty = threadIdx.x >> 5;
  #pragma unroll
  for (int j=0;j<4;j++){
    int dd = ty + 8*j;
    t[dd][tx] = xx[(b*DD + d0+dd)*LL + l0 + tx];
  }
  __syncthreads();
  #pragma unroll
  for (int j=0;j<4;j++){
    int ll = ty + 8*j;
    int l = l0 + ll;
    float v = t[tx][ll];
    int lw = (l%40)*40 + l/40;
    xs[((b*2+0)*LL + l )*DD + d0 + tx] = v;
    xs[((b*2+1)*LL + lw)*DD + d0 + tx] = v;
  }
}

// 6c: spatial transpose keeping d-major
__global__ void k_xw(const float* xx, float* xw1){
  __shared__ float sm[40*41];
  int bd = blockIdx.x;
  const float* ip = xx + bd*LL;
  float* op = xw1 + bd*LL;
  for (int i=threadIdx.x; i<LL; i+=256){
    sm[(i/40)*41 + (i%40)] = ip[i];
  }
  __syncthreads();
  for (int i=threadIdx.x; i<LL; i+=256){
    op[i] = sm[(i%40)*41 + (i/40)];
  }
}

// 7: xd (bk,38,L), lanes over l (coalesced)
__global__ void k_xdbl(const float* xx, const float* xw1, const float* w, float* xd){
  int idx = blockIdx.x*256 + threadIdx.x;
  if (idx >= BB*KK*10*LL) return;
  int l = idx%LL, cq = (idx/LL)%10, bk = idx/(LL*10);
  int k = bk%KK, b = bk/KK;
  const float* base = ((k&1)? xw1 : xx) + b*DD*LL;
  int row = (k<2)? l : (LL-1-l);
  int jmax = (cq < 8)? 4 : 3;
  const float* w0 = w + (k*38+cq)*DD;
  float acc[4] = {0.f,0.f,0.f,0.f};
  for (int d=0;d<DD;d++){
    float xv = base[d*LL + row];
    #pragma unroll
    for (int j=0;j<4;j++) acc[j] += w0[j*10*DD + d]*xv;
  }
  float* out = xd + bk*38*LL;
  for (int j=0;j<jmax;j++) out[(cq+10*j)*LL + l] = acc[j];
}

// 9: scan pass1 — thread = (bk,c,dh,g,d32): 8 states each; P=prod dA, S=chunk-end state
__global__ void k_scan1(const float* xs, const float* xd, const float* dtw, const float* dtb,
                        const float* Alog, float* Pb, float* Sb){
  int idx = blockIdx.x*256 + threadIdx.x;
  if (idx >= BB*KK*NCH*DH*NG*32) return;
  int d32 = idx & 31;
  int g   = (idx>>5) & 1;
  int rest = idx >> 6;             // (bk*NCH + c)*DH + dh
  int dh = rest % DH;
  int rest2 = rest / DH;
  int c = rest2 % NCH;
  int bk = rest2 / NCH;
  int d = dh*32 + d32;
  int k = bk%KK, b = bk/KK;
  int kd = k*DD+d;
  float w6[RR];
  #pragma unroll
  for (int r=0;r<RR;r++) w6[r] = dtw[kd*RR+r];
  float bias = dtb[kd];
  float A2[NH], P[NH], S[NH];
  #pragma unroll
  for (int n=0;n<NH;n++){ A2[n] = -expf(Alog[kd*NN + g*NH + n])*LOG2E; P[n]=1.f; S[n]=0.f; }
  int k01 = k&1;
  const float* xsb = xs + (b*2+k01)*LL*DD;
  const float* xdb = xd + bk*38*LL;
  bool rev = (k>=2);
  for (int j=0;j<CLEN;j++){
    int t = c*CLEN + j;
    int row = rev ? (LL-1-t) : t;
    float dtr = bias;
    #pragma unroll
    for (int r=0;r<RR;r++) dtr += w6[r]*xdb[r*LL + t];
    float dt = softplusf(dtr);
    float xv = xsb[row*DD + d];
    float u = dt*xv;
    #pragma unroll
    for (int n=0;n<NH;n++){
      float dA = exp2f(dt*A2[n]);
      P[n] *= dA;
      S[n] = S[n]*dA + u*xdb[(RR+g*NH+n)*LL + t];
    }
  }
  int off = ((bk*DD+d)*NCH + c)*NN + g*NH;
  #pragma unroll
  for (int n=0;n<NH;n++){ Pb[off+n]=P[n]; Sb[off+n]=S[n]; }
}

// 10: inter-chunk scan; writes Hin in-place over Pb
__global__ void k_scanmid(float* Pb, const float* Sb){
  int idx = blockIdx.x*256 + threadIdx.x;
  if (idx >= BB*KK*DD*NN) return;
  int n = idx%NN, bkd = idx/NN;
  float h = 0.f;
  for (int c=0;c<NCH;c++){
    int o = (bkd*NCH + c)*NN + n;
    float p = Pb[o], s = Sb[o];
    Pb[o] = h;
    h = p*h + s;
  }
}

// 11: scan pass2 — replay with carry-in; wave-internal y combine; atomic into Y (b,l,d)
__global__ void k_scan2(const float* xs, const float* xd, const float* dtw, const float* dtb,
                        const float* Alog, const float* Hin, const float* Ds, float* Y){
  int idx = blockIdx.x*256 + threadIdx.x;
  if (idx >= BB*KK*NCH*DH*NG*32) return;
  int d32 = idx & 31;
  int g   = (idx>>5) & 1;
  int rest = idx >> 6;
  int dh = rest % DH;
  int rest2 = rest / DH;
  int c = rest2 % NCH;
  int bk = rest2 / NCH;
  int d = dh*32 + d32;
  int k = bk%KK, b = bk/KK;
  int kd = k*DD+d;
  float w6[RR];
  #pragma unroll
  for (int r=0;r<RR;r++) w6[r] = dtw[kd*RR+r];
  float bias = dtb[kd];
  float A2[NH], h[NH];
  int hoff = ((bk*DD+d)*NCH + c)*NN + g*NH;
  #pragma unroll
  for (int n=0;n<NH;n++){ A2[n] = -expf(Alog[kd*NN + g*NH + n])*LOG2E; h[n] = Hin[hoff+n]; }
  float Dv = Ds[kd];
  int k01 = k&1;
  const float* xsb = xs + (b*2+k01)*LL*DD;
  const float* xdb = xd + bk*38*LL;
  float* yb = Y + b*LL*DD;
  bool rev = (k>=2);
  for (int j=0;j<CLEN;j++){
    int t = c*CLEN + j;
    int row = rev ? (LL-1-t) : t;
    float dtr = bias;
    #pragma unroll
    for (int r=0;r<RR;r++) dtr += w6[r]*xdb[r*LL + t];
    float dt = softplusf(dtr);
    float xv = xsb[row*DD + d];
    float u = dt*xv;
    float y = 0.f;
    #pragma unroll
    for (int n=0;n<NH;n++){
      float dA = exp2f(dt*A2[n]);
      h[n] = h[n]*dA + u*xdb[(RR+g*NH+n)*LL + t];
      y += h[n]*xdb[(RR+NN+g*NH+n)*LL + t];
    }
    y += __shfl_xor(y, 32, 64);   // combine the two n-halves (lane partners differ in bit 5)
    if (g==0){
      int p = xpos(k, t);
      atomicAdd(&yb[p*DD + d], y + Dv*xv);
    }
  }
}

// 13: layernorm over d (wave per row), * onorm, * z1 -> YZ (b,l,d)
__global__ void k_ln(const float* Y, const float* og, const float* ob, const float* z1, float* yz){
  int r = blockIdx.x*4 + (threadIdx.x >> 6);
  int lane = threadIdx.x & 63;
  int b = r/LL, l = r%LL;
  const float* yp = Y + r*DD;
  float v0 = yp[lane], v1 = yp[lane+64], v2 = yp[lane+128];
  float s = v0+v1+v2;
  #pragma unroll
  for (int off=32; off>0; off>>=1) s += __shfl_xor(s, off, 64);
  float m = s*(1.0f/DD);
  float t0=v0-m, t1=v1-m, t2=v2-m;
  float vv = t0*t0+t1*t1+t2*t2;
  #pragma unroll
  for (int off=32; off>0; off>>=1) vv += __shfl_xor(vv, off, 64);
  float rs = rsqrtf(vv*(1.0f/DD) + 1e-5f);
  #pragma unroll
  for (int i=0;i<3;i++){
    int d = lane + 64*i;
    float t = (i==0?t0:(i==1?t1:t2));
    float o = (t*rs*og[d] + ob[d]) * z1[(b*DD+d)*LL + l];
    yz[r*DD + d] = o;
  }
}

// 14: x2 = res1 + conv1x1(yz(b,l,d), out_proj_w); xb = bn_n2(x2)  [4-way tile]
__global__ void k_outproj(const float* yz, const float* w, const float* res, const float* g, const float* b_,
                          float* x2, float* xb){
  int idx = blockIdx.x*256 + threadIdx.x;
  if (idx >= BB*24*LL) return;
  int l = idx%LL, og = (idx/LL)%24, b = idx/(LL*24);
  const float* ip = yz + (b*LL+l)*DD;
  float acc[4] = {0.f,0.f,0.f,0.f};
  for (int d=0;d<DD;d++){
    float yv = ip[d];
    #pragma unroll
    for (int j=0;j<4;j++) acc[j] += w[(og+24*j)*DD+d]*yv;
  }
  #pragma unroll
  for (int j=0;j<4;j++){
    int o = og+24*j;
    float v = res[(b*CC+o)*LL+l] + acc[j];
    x2[(b*CC+o)*LL+l] = v;
    xb[(b*CC+o)*LL+l] = v*(g[o]*BNS) + b_[o];
  }
}

// 15: spatial mean per (b,c) — block per row
__global__ void k_gmean(const float* xb, float* gv){
  __shared__ float sm[4];
  int bc = blockIdx.x;
  int tid = threadIdx.x;
  const float* p = xb + bc*LL;
  float s = 0.f;
  for (int l=tid; l<LL; l+=256) s += p[l];
  #pragma unroll
  for (int off=32; off>0; off>>=1) s += __shfl_xor(s, off, 64);
  if ((tid&63)==0) sm[tid>>6] = s;
  __syncthreads();
  if (tid==0) gv[bc] = (sm[0]+sm[1]+sm[2]+sm[3])*(1.0f/LL);
}

// 16: router
__global__ void k_router(const float* gv, const float* rw, const float* rb, float* wm){
  int b = threadIdx.x;
  if (b >= BB) return;
  float lg[EE];
  for (int e=0;e<EE;e++){
    float a = rb[e];
    for (int c=0;c<CC;c++) a += gv[b*CC+c]*rw[e*CC+c];
    lg[e] = a*0.5f;
  }
  float mx = lg[0];
  for (int e=1;e<EE;e++) mx = fmaxf(mx, lg[e]);
  float p[EE], s = 0.f;
  for (int e=0;e<EE;e++){ p[e] = __expf(lg[e]-mx); s += p[e]; }
  for (int e=0;e<EE;e++) p[e] /= s;
  int i1 = 0;
  for (int e=1;e<EE;e++) if (p[e] > p[i1]) i1 = e;
  int i2 = -1;
  for (int e=0;e<EE;e++){ if (e==i1) continue; if (i2<0 || p[e]>p[i2]) i2 = e; }
  float tot = p[i1]+p[i2];
  for (int e=0;e<EE;e++) wm[b*EE+e] = 0.f;
  wm[b*EE+i1] = p[i1]/tot;
  wm[b*EE+i2] = p[i2]/tot;
}

// 17: per-expert dwconv+gelu (skip unselected)
__global__ void k_moedw(const float* xb, const float* dw, const float* db, const float* wm, float* he){
  int idx = blockIdx.x*256 + threadIdx.x;
  if (idx >= EE*BB*CC*LL) return;
  int l = idx%LL, c = (idx/LL)%CC, b = (idx/(LL*CC))%BB, e = idx/(LL*CC*BB);
  if (wm[b*EE+e] == 0.f) return;
  int y = l/40, x0 = l%40;
  const float* ip = xb + (b*CC+c)*LL;
  float acc = 0.f;
  #pragma unroll
  for (int ky=0;ky<3;ky++){
    int yy = y+ky-1; if (yy<0||yy>=40) continue;
    #pragma unroll
    for (int kx=0;kx<3;kx++){
      int xx = x0+kx-1; if (xx<0||xx>=40) continue;
      acc += dw[(e*CC+c)*9+ky*3+kx] * ip[yy*40+xx];
    }
  }
  he[((e*BB+b)*CC+c)*LL+l] = geluf(acc + db[e*CC+c]);
}

// 18: out = x2 + sum_e wm*(conv1x1(he_e)+pb_e)  [4-way tile], dtype-branch store
__global__ void k_final(const float* he, const float* pw, const float* pb, const float* wm,
                        const float* x2, void* out, const void* dsraw){
  bool f32 = (((const unsigned*)dsraw)[0] == 0x3F800000u);
  int idx = blockIdx.x*256 + threadIdx.x;
  if (idx >= BB*24*LL) return;
  int l = idx%LL, og = (idx/LL)%24, b = idx/(LL*24);
  float acc[4];
  #pragma unroll
  for (int j=0;j<4;j++) acc[j] = x2[(b*CC+og+24*j)*LL+l];
  for (int e=0;e<EE;e++){
    float wv = wm[b*EE+e];
    if (wv == 0.f) continue;
    const float* hp = he + (e*BB+b)*CC*LL + l;
    float s[4];
    #pragma unroll
    for (int j=0;j<4;j++) s[j] = pb[e*CC+og+24*j];
    for (int c=0;c<CC;c++){
      float hv = hp[c*LL];
      #pragma unroll
      for (int j=0;j<4;j++) s[j] += pw[(e*CC+og+24*j)*CC+c]*hv;
    }
    #pragma unroll
    for (int j=0;j<4;j++) acc[j] += wv*s[j];
  }
  #pragma unroll
  for (int j=0;j<4;j++){
    int o = (b*CC+og+24*j)*LL+l;
    if (f32) ((float*)out)[o] = acc[j];
    else     ((bf16*)out)[o] = __float2bfloat16(acc[j]);
  }
}

extern "C" void kernel_launch(void* const* d_in, const int* in_sizes, int n_in,
                              void* d_out, int out_size, void* d_ws, size_t ws_size,
                              hipStream_t stream) {
  static const int cum[34] = {
    0, 614400, 623616, 623712, 623808, 624672, 624768, 624864, 624960,
    634176, 634272, 643488, 643584, 643680, 643776, 680640, 682368, 682560,
    711744, 716352, 717120, 729408, 730176, 730368, 730560, 748992, 749088,
    749184, 749568, 749572, 753028, 753412, 790276, 790660
  };
  float* ws = (float*)d_ws;
  const float* cv[33];
  P33 ps;
  for (int i=0;i<33;i++){ ps.p[i] = d_in[i]; cv[i] = ws + cum[i]; }

  const float* c_x    = cv[0];
  const float* c_pw   = cv[1];
  const float* c_bn0g = cv[2];
  const float* c_bn0b = cv[3];
  const float* c_f1w  = cv[4];
  const float* c_f1b  = cv[5];
  const float* c_lbg  = cv[6];
  const float* c_lbb  = cv[7];
  const float* c_f2w  = cv[8];
  const float* c_f2b  = cv[9];
  const float* c_f3w  = cv[10];
  const float* c_f3b  = cv[11];
  const float* c_n1g  = cv[12];
  const float* c_n1b  = cv[13];
  const float* c_ipw  = cv[14];
  const float* c_cw   = cv[15];
  const float* c_cb   = cv[16];
  const float* c_xpw  = cv[17];
  const float* c_dtw  = cv[18];
  const float* c_dtb  = cv[19];
  const float* c_al   = cv[20];
  const float* c_ds   = cv[21];
  const float* c_ong  = cv[22];
  const float* c_onb  = cv[23];
  const float* c_opw  = cv[24];
  const float* c_n2g  = cv[25];
  const float* c_n2b  = cv[26];
  const float* c_rw   = cv[27];
  const float* c_rb   = cv[28];
  const float* c_mdw  = cv[29];
  const float* c_mdb  = cv[30];
  const float* c_mpw  = cv[31];
  const float* c_mpb  = cv[32];

  // arena (floats), total 13,682,944 = 54.7 MB
  float* R   = ws +   790784;  // 614400   k_proj -> k_outproj
  float* T1  = ws +  1405184;  // slot B: T1 -> X1 -> [XW1 window] -> X2
  float* X1  = T1;
  float* X2  = T1;
  float* T2  = ws +  2019584;  // slot C: T2 -> [XW1 window] -> XB
  float* XB  = T2;
  float* XW1 = T1;             // spans B+C (1,228,800), live k_xw -> k_xdbl only
  float* XXP = ws +  2633984;  // slot D: XXP -> Y (1,228,800)
  float* Y   = XXP;
  float* Z1  = ws +  3862784;  // 1,228,800, live to k_ln
  float* XX  = ws +  5091584;  // slot F: XX -> YZ (1,228,800)
  float* YZ  = XX;
  float* XS  = ws +  6320384;  // slot G: XS (2,457,600) -> HE
  float* HE  = XS;
  float* XD  = ws +  8777984;  // slot H: XD (972,800) -> GV/WM
  float* GV  = XD;
  float* WM  = XD + 384;
  float* PB  = ws +  9750784;  // 1,966,080 (Hin in-place)
  float* SB  = ws + 11716864;  // 1,966,080

  const int T = 256;
  k_convert  <<<(NTOT+T-1)/T, T, 0, stream>>>(ps, ws);
  k_proj     <<<(BB*24*LL+T-1)/T, T, 0, stream>>>(c_x, c_pw, c_bn0g, c_bn0b, R);
  k_dwbn     <<<(BB*CC*LL+T-1)/T, T, 0, stream>>>(R, c_f1w, c_f1b, c_lbg, c_lbb, T1);
  k_fc_gelu  <<<(BB*24*LL+T-1)/T, T, 0, stream>>>(T1, c_f2w, c_f2b, T2);
  k_fc_res_bn<<<(BB*24*LL+T-1)/T, T, 0, stream>>>(T2, c_f3w, c_f3b, R, c_n1g, c_n1b, X1);
  k_inproj   <<<(BB*96*LL+T-1)/T, T, 0, stream>>>(X1, c_ipw, XXP, Z1);
  k_ssconv   <<<(BB*DD*LL+T-1)/T, T, 0, stream>>>(XXP, c_cw, c_cb, XX);
  k_xs       <<<1200, T, 0, stream>>>(XX, XS);
  k_xw       <<<BB*DD, T, 0, stream>>>(XX, XW1);
  hipMemsetAsync(Y, 0, (size_t)BB*DD*LL*sizeof(float), stream);   // Y aliases XXP (dead)
  k_xdbl     <<<(BB*KK*10*LL+T-1)/T, T, 0, stream>>>(XX, XW1, c_xpw, XD);
  k_scan1    <<<(BB*KK*NCH*DD*NG+T-1)/T, T, 0, stream>>>(XS, XD, c_dtw, c_dtb, c_al, PB, SB);
  k_scanmid  <<<(BB*KK*DD*NN+T-1)/T, T, 0, stream>>>(PB, SB);
  k_scan2    <<<(BB*KK*NCH*DD*NG+T-1)/T, T, 0, stream>>>(XS, XD, c_dtw, c_dtb, c_al, PB, c_ds, Y);
  k_ln       <<<1600, T, 0, stream>>>(Y, c_ong, c_onb, Z1, YZ);
  k_outproj  <<<(BB*24*LL+T-1)/T, T, 0, stream>>>(YZ, c_opw, R, c_n2g, c_n2b, X2, XB);
  k_gmean    <<<BB*CC, T, 0, stream>>>(XB, GV);
  k_router   <<<1, 64, 0, stream>>>(GV, c_rw, c_rb, WM);
  k_moedw    <<<(EE*BB*CC*LL+T-1)/T, T, 0, stream>>>(XB, c_mdw, c_mdb, WM, HE);
  k_final    <<<(BB*24*LL+T-1)/T, T, 0, stream>>>(HE, c_mpw, c_mpb, WM, X2, d_out, d_in[21]);
}

// Round 6
// 442.179 us; speedup vs baseline: 2.4921x; 1.1617x over previous
//
#include <hip/hip_runtime.h>
#include <hip/hip_bf16.h>
#include <math.h>

#define BB 4
#define CC 96
#define LL 1600
#define DD 192
#define KK 4
#define RR 6
#define NN 16
#define EE 4
#define NCH 40
#define CLEN 40

typedef __hip_bfloat16 bf16;

__device__ __forceinline__ float geluf(float x){ return 0.5f*x*(1.0f+erff(x*0.70710678118654752440f)); }
__device__ __forceinline__ float softplusf(float x){ return (x>20.0f)? x : __logf(1.0f+__expf(x)); }
#define BNS rsqrtf(1.0f + 1e-5f)
#define LOG2E 1.44269504088896340736f

// hw position for scan-direction k at scan index t
__device__ __forceinline__ int xpos(int k, int l){
  if (k==0) return l;
  if (k==2) return LL-1-l;
  int t = (k==1)? l : (LL-1-l);
  return (t%40)*40 + t/40;   // H==W==40 transpose map (involution)
}

// ---- input conversion: everything -> fp32 in workspace ----
struct P33 { const void* p[33]; };
#define NTOT 790660
__device__ const int g_cum[34] = {
  0, 614400, 623616, 623712, 623808, 624672, 624768, 624864, 624960,
  634176, 634272, 643488, 643584, 643680, 643776, 680640, 682368, 682560,
  711744, 716352, 717120, 729408, 730176, 730368, 730560, 748992, 749088,
  749184, 749568, 749572, 753028, 753412, 790276, 790660
};

__global__ void k_convert(P33 ps, float* cv){
  bool f32 = (((const unsigned*)ps.p[21])[0] == 0x3F800000u);
  int idx = blockIdx.x*256 + threadIdx.x;
  if (idx >= NTOT) return;
  int lo=0, hi=33;
  while (lo+1<hi){ int mid=(lo+hi)>>1; if (idx >= g_cum[mid]) lo=mid; else hi=mid; }
  int local = idx - g_cum[lo];
  float v = f32 ? ((const float*)ps.p[lo])[local]
                : __bfloat162float(((const bf16*)ps.p[lo])[local]);
  cv[idx] = v;
}

// ---------- LDS-tiled 1x1 convs: block = (b, l-tile 64, o-tile 32) ----------
// 1: x = silu(bn0(conv1x1(x, proj_w)))
__global__ void k_proj(const float* x, const float* w, const float* g, const float* b_, float* out){
  __shared__ float lx[96*64];
  int bid = blockIdx.x;
  int ot = bid%3, lt = (bid/3)%25, b = bid/75;
  int l0 = lt*64, ob = ot*32;
  const float* inb = x + b*CC*LL;
  for (int i=threadIdx.x; i<96*64; i+=256) lx[i] = inb[(i>>6)*LL + l0 + (i&63)];
  __syncthreads();
  int oq = threadIdx.x>>5, lq = threadIdx.x&31;
  float acc[4][2] = {};
  #pragma unroll 4
  for (int c=0;c<96;c++){
    float x0 = lx[c*64+lq], x1 = lx[c*64+lq+32];
    #pragma unroll
    for (int jo=0;jo<4;jo++){
      float wv = w[(ob+oq+8*jo)*CC + c];
      acc[jo][0] += wv*x0; acc[jo][1] += wv*x1;
    }
  }
  #pragma unroll
  for (int jo=0;jo<4;jo++){
    int o = ob+oq+8*jo;
    float sc = g[o]*BNS, bb = b_[o];
    #pragma unroll
    for (int jl=0;jl<2;jl++){
      float v = acc[jo][jl]*sc + bb;
      out[(b*CC+o)*LL + l0+lq+32*jl] = v/(1.0f+__expf(-v));
    }
  }
}

// 3: gelu(conv1x1 + bias)
__global__ void k_fc_gelu(const float* in, const float* w, const float* bias, float* out){
  __shared__ float lx[96*64];
  int bid = blockIdx.x;
  int ot = bid%3, lt = (bid/3)%25, b = bid/75;
  int l0 = lt*64, ob = ot*32;
  const float* inb = in + b*CC*LL;
  for (int i=threadIdx.x; i<96*64; i+=256) lx[i] = inb[(i>>6)*LL + l0 + (i&63)];
  __syncthreads();
  int oq = threadIdx.x>>5, lq = threadIdx.x&31;
  float acc[4][2] = {};
  #pragma unroll 4
  for (int c=0;c<96;c++){
    float x0 = lx[c*64+lq], x1 = lx[c*64+lq+32];
    #pragma unroll
    for (int jo=0;jo<4;jo++){
      float wv = w[(ob+oq+8*jo)*CC + c];
      acc[jo][0] += wv*x0; acc[jo][1] += wv*x1;
    }
  }
  #pragma unroll
  for (int jo=0;jo<4;jo++){
    int o = ob+oq+8*jo;
    float bb = bias[o];
    out[(b*CC+o)*LL + l0+lq]    = geluf(acc[jo][0]+bb);
    out[(b*CC+o)*LL + l0+lq+32] = geluf(acc[jo][1]+bb);
  }
}

// 4: X1 = bn_n1( res + conv1x1(in) + bias )
__global__ void k_fc_res_bn(const float* in, const float* w, const float* bias, const float* res,
                            const float* g, const float* b_, float* out){
  __shared__ float lx[96*64];
  int bid = blockIdx.x;
  int ot = bid%3, lt = (bid/3)%25, b = bid/75;
  int l0 = lt*64, ob = ot*32;
  const float* inb = in + b*CC*LL;
  for (int i=threadIdx.x; i<96*64; i+=256) lx[i] = inb[(i>>6)*LL + l0 + (i&63)];
  __syncthreads();
  int oq = threadIdx.x>>5, lq = threadIdx.x&31;
  float acc[4][2] = {};
  #pragma unroll 4
  for (int c=0;c<96;c++){
    float x0 = lx[c*64+lq], x1 = lx[c*64+lq+32];
    #pragma unroll
    for (int jo=0;jo<4;jo++){
      float wv = w[(ob+oq+8*jo)*CC + c];
      acc[jo][0] += wv*x0; acc[jo][1] += wv*x1;
    }
  }
  #pragma unroll
  for (int jo=0;jo<4;jo++){
    int o = ob+oq+8*jo;
    float bb = bias[o], sc = g[o]*BNS, b2 = b_[o];
    #pragma unroll
    for (int jl=0;jl<2;jl++){
      int pos = (b*CC+o)*LL + l0+lq+32*jl;
      float v = acc[jo][jl] + bb + res[pos];
      out[pos] = v*sc + b2;
    }
  }
}

// 5: inproj: 12 o-tiles; tiles 0-5 -> xxp (b,d,l); tiles 6-11 -> z1 (b,l,d) via LDS transpose
__global__ void k_inproj(const float* in, const float* w, float* xxp, float* z1){
  __shared__ float lx[96*64];
  int bid = blockIdx.x;
  int ot = bid%12, lt = (bid/12)%25, b = bid/300;
  int l0 = lt*64, ob = ot*32;
  const float* inb = in + b*CC*LL;
  for (int i=threadIdx.x; i<96*64; i+=256) lx[i] = inb[(i>>6)*LL + l0 + (i&63)];
  __syncthreads();
  int oq = threadIdx.x>>5, lq = threadIdx.x&31;
  float acc[4][2] = {};
  #pragma unroll 4
  for (int c=0;c<96;c++){
    float x0 = lx[c*64+lq], x1 = lx[c*64+lq+32];
    #pragma unroll
    for (int jo=0;jo<4;jo++){
      float wv = w[(ob+oq+8*jo)*CC + c];
      acc[jo][0] += wv*x0; acc[jo][1] += wv*x1;
    }
  }
  if (ot < 6){
    #pragma unroll
    for (int jo=0;jo<4;jo++){
      int oc = ob+oq+8*jo;
      xxp[(b*DD+oc)*LL + l0+lq]    = acc[jo][0];
      xxp[(b*DD+oc)*LL + l0+lq+32] = acc[jo][1];
    }
  } else {
    __syncthreads();
    #pragma unroll
    for (int jo=0;jo<4;jo++){
      int oo = oq+8*jo;
      lx[lq*33 + oo]      = geluf(acc[jo][0]);
      lx[(lq+32)*33 + oo] = geluf(acc[jo][1]);
    }
    __syncthreads();
    int zb = ob - 192;
    for (int i=threadIdx.x; i<64*32; i+=256){
      int u = i>>5, oo = i&31;
      z1[(b*LL + l0+u)*DD + zb + oo] = lx[u*33 + oo];
    }
  }
}

// 6: xx = gelu(dwconv3(xx_pre))
__global__ void k_ssconv(const float* in, const float* w, const float* bias, float* out){
  int idx = blockIdx.x*256 + threadIdx.x;
  if (idx >= BB*DD*LL) return;
  int l = idx%LL, d = (idx/LL)%DD, b = idx/(LL*DD);
  int y = l/40, x0 = l%40;
  const float* ip = in + (b*DD+d)*LL;
  float acc = 0.f;
  #pragma unroll
  for (int ky=0;ky<3;ky++){
    int yy = y+ky-1; if (yy<0||yy>=40) continue;
    #pragma unroll
    for (int kx=0;kx<3;kx++){
      int xx = x0+kx-1; if (xx<0||xx>=40) continue;
      acc += w[d*9+ky*3+kx] * ip[yy*40+xx];
    }
  }
  out[idx] = geluf(acc + bias[d]);
}

// 2: h = bn(dwconv3)
__global__ void k_dwbn(const float* in, const float* w, const float* bias, const float* g, const float* b_, float* out){
  int idx = blockIdx.x*256 + threadIdx.x;
  if (idx >= BB*CC*LL) return;
  int l = idx%LL, c = (idx/LL)%CC, b = idx/(LL*CC);
  int y = l/40, x0 = l%40;
  const float* ip = in + (b*CC+c)*LL;
  float acc = 0.f;
  #pragma unroll
  for (int ky=0;ky<3;ky++){
    int yy = y+ky-1; if (yy<0||yy>=40) continue;
    #pragma unroll
    for (int kx=0;kx<3;kx++){
      int xx = x0+kx-1; if (xx<0||xx>=40) continue;
      acc += w[c*9+ky*3+kx] * ip[yy*40+xx];
    }
  }
  acc += bias[c];
  out[idx] = acc*(g[c]*BNS) + b_[c];
}

// 6b: LDS-tiled transpose -> XS (b,k01,l,d)
__global__ void k_xs(const float* xx, float* xs){
  __shared__ float t[32][33];
  int bid = blockIdx.x;
  int lt = bid % 50, dt = (bid/50)%6, b = bid/300;
  int l0 = lt*32, d0 = dt*32;
  int tx = threadIdx.x & 31, ty = threadIdx.x >> 5;
  #pragma unroll
  for (int j=0;j<4;j++){
    int dd = ty + 8*j;
    t[dd][tx] = xx[(b*DD + d0+dd)*LL + l0 + tx];
  }
  __syncthreads();
  #pragma unroll
  for (int j=0;j<4;j++){
    int ll = ty + 8*j;
    int l = l0 + ll;
    float v = t[tx][ll];
    int lw = (l%40)*40 + l/40;
    xs[((b*2+0)*LL + l )*DD + d0 + tx] = v;
    xs[((b*2+1)*LL + lw)*DD + d0 + tx] = v;
  }
}

// 6c: spatial transpose keeping d-major
__global__ void k_xw(const float* xx, float* xw1){
  __shared__ float sm[40*41];
  int bd = blockIdx.x;
  const float* ip = xx + bd*LL;
  float* op = xw1 + bd*LL;
  for (int i=threadIdx.x; i<LL; i+=256) sm[(i/40)*41 + (i%40)] = ip[i];
  __syncthreads();
  for (int i=threadIdx.x; i<LL; i+=256) op[i] = sm[(i%40)*41 + (i/40)];
}

// 7: xd (bk,t,38): block = (bk, 64-t tile); weights wave-uniform, x coalesced, LDS-transposed store
__global__ void k_xdbl(const float* xx, const float* xw1, const float* w, float* xd){
  __shared__ float lt_[64*41];
  int bid = blockIdx.x;           // BB*KK*25
  int tt = bid % 25, bk = bid / 25;
  int k = bk & 3, b = bk >> 2;
  int t0 = tt*64;
  int cg = threadIdx.x >> 6, tl = threadIdx.x & 63;
  int t = t0 + tl;
  int row = (k<2)? t : (LL-1-t);
  const float* base = ((k&1)? xw1 : xx) + b*DD*LL + row;
  const float* wp[10];
  #pragma unroll
  for (int j=0;j<10;j++){
    int c = cg + 4*j; if (c>37) c = 37;
    wp[j] = w + (k*38+c)*DD;
  }
  float acc[10] = {};
  for (int d=0; d<DD; d++){
    float xv = base[d*LL];
    #pragma unroll
    for (int j=0;j<10;j++) acc[j] += wp[j][d]*xv;
  }
  #pragma unroll
  for (int j=0;j<10;j++){
    int c = cg + 4*j;
    if (c < 38) lt_[tl*41 + c] = acc[j];
  }
  __syncthreads();
  float* ob = xd + (bk*LL + t0)*38;
  for (int i=threadIdx.x; i<64*38; i+=256) ob[i] = lt_[(i/38)*41 + (i%38)];
}

// 9: scan pass1 — wave = 16 d x 4 g; per-thread 4 states
__global__ void k_scan1(const float* xs, const float* xd, const float* dtw, const float* dtb,
                        const float* Alog, float* Pb, float* Sb){
  int idx = blockIdx.x*256 + threadIdx.x;
  int lane = idx & 63;
  int d16 = lane & 15, g = lane >> 4;
  int wv_ = (idx>>6) % 12;
  int rest = (idx>>6) / 12;
  int c = rest % NCH, bk = rest / NCH;
  int d = wv_*16 + d16;
  int k = bk & 3, b = bk >> 2;
  int kd = k*DD + d;
  float w6[RR];
  #pragma unroll
  for (int r=0;r<RR;r++) w6[r] = dtw[kd*RR+r];
  float bias = dtb[kd];
  float A2[4], P[4]={1.f,1.f,1.f,1.f}, S[4]={0.f,0.f,0.f,0.f};
  #pragma unroll
  for (int n=0;n<4;n++) A2[n] = -expf(Alog[kd*NN + g*4 + n])*LOG2E;
  const float* xsb = xs + ((b*2)+(k&1))*LL*DD;
  const float* xr = xd + (bk*LL + c*CLEN)*38;
  bool rev = (k>=2);
  int t0 = c*CLEN;
  for (int j=0;j<CLEN;j++){
    int t = t0+j;
    int row = rev? (LL-1-t) : t;
    float dtr = bias;
    #pragma unroll
    for (int r=0;r<RR;r++) dtr += w6[r]*xr[r];
    float dt = softplusf(dtr);
    float xv = xsb[row*DD + d];
    float u = dt*xv;
    #pragma unroll
    for (int n=0;n<4;n++){
      float dA = exp2f(dt*A2[n]);
      P[n] *= dA;
      S[n] = S[n]*dA + u*xr[RR + g*4 + n];
    }
    xr += 38;
  }
  int off = ((bk*DD + d)*NCH + c)*NN + g*4;
  *(float4*)(Pb+off) = make_float4(P[0],P[1],P[2],P[3]);
  *(float4*)(Sb+off) = make_float4(S[0],S[1],S[2],S[3]);
}

// 10: inter-chunk scan; Hin in-place over Pb
__global__ void k_scanmid(float* Pb, const float* Sb){
  int idx = blockIdx.x*256 + threadIdx.x;
  if (idx >= BB*KK*DD*NN) return;
  int n = idx%NN, bkd = idx/NN;
  float h = 0.f;
  for (int c=0;c<NCH;c++){
    int o = (bkd*NCH + c)*NN + n;
    float p = Pb[o], s = Sb[o];
    Pb[o] = h;
    h = p*h + s;
  }
}

// 11: scan pass2 — wave = 16 d x 4 g; shfl-combine y; atomic into Y (b,l,d)
__global__ void k_scan2(const float* xs, const float* xd, const float* dtw, const float* dtb,
                        const float* Alog, const float* Hin, const float* Ds, float* Y){
  int idx = blockIdx.x*256 + threadIdx.x;
  int lane = idx & 63;
  int d16 = lane & 15, g = lane >> 4;
  int wv_ = (idx>>6) % 12;
  int rest = (idx>>6) / 12;
  int c = rest % NCH, bk = rest / NCH;
  int d = wv_*16 + d16;
  int k = bk & 3, b = bk >> 2;
  int kd = k*DD + d;
  float w6[RR];
  #pragma unroll
  for (int r=0;r<RR;r++) w6[r] = dtw[kd*RR+r];
  float bias = dtb[kd];
  int off = ((bk*DD + d)*NCH + c)*NN + g*4;
  float4 h4 = *(const float4*)(Hin+off);
  float h[4] = {h4.x, h4.y, h4.z, h4.w};
  float A2[4];
  #pragma unroll
  for (int n=0;n<4;n++) A2[n] = -expf(Alog[kd*NN + g*4 + n])*LOG2E;
  float Dv = Ds[kd];
  const float* xsb = xs + ((b*2)+(k&1))*LL*DD;
  const float* xr = xd + (bk*LL + c*CLEN)*38;
  float* yb = Y + b*LL*DD;
  bool rev = (k>=2);
  int t0 = c*CLEN;
  for (int j=0;j<CLEN;j++){
    int t = t0+j;
    int row = rev? (LL-1-t) : t;
    float dtr = bias;
    #pragma unroll
    for (int r=0;r<RR;r++) dtr += w6[r]*xr[r];
    float dt = softplusf(dtr);
    float xv = xsb[row*DD + d];
    float u = dt*xv;
    float y = 0.f;
    #pragma unroll
    for (int n=0;n<4;n++){
      float dA = exp2f(dt*A2[n]);
      h[n] = h[n]*dA + u*xr[RR + g*4 + n];
      y += h[n]*xr[RR + NN + g*4 + n];
    }
    y += __shfl_xor(y, 16, 64);
    y += __shfl_xor(y, 32, 64);
    if (g==0){
      int p = xpos(k, t);
      atomicAdd(&yb[p*DD + d], y + Dv*xv);
    }
    xr += 38;
  }
}

// 13: layernorm over d (wave per row), * onorm, * z1(b,l,d) -> YZ (b,l,d)
__global__ void k_ln(const float* Y, const float* og, const float* ob, const float* z1, float* yz){
  int r = blockIdx.x*4 + (threadIdx.x >> 6);
  int lane = threadIdx.x & 63;
  const float* yp = Y + r*DD;
  float v0 = yp[lane], v1 = yp[lane+64], v2 = yp[lane+128];
  float s = v0+v1+v2;
  #pragma unroll
  for (int off=32; off>0; off>>=1) s += __shfl_xor(s, off, 64);
  float m = s*(1.0f/DD);
  float t0=v0-m, t1=v1-m, t2=v2-m;
  float vv = t0*t0+t1*t1+t2*t2;
  #pragma unroll
  for (int off=32; off>0; off>>=1) vv += __shfl_xor(vv, off, 64);
  float rs = rsqrtf(vv*(1.0f/DD) + 1e-5f);
  #pragma unroll
  for (int i=0;i<3;i++){
    int d = lane + 64*i;
    float t = (i==0?t0:(i==1?t1:t2));
    yz[r*DD + d] = (t*rs*og[d] + ob[d]) * z1[r*DD + d];
  }
}

// 14: outproj tiled: input YZ (b,l,d) CIN=192
__global__ void k_outproj(const float* yz, const float* w, const float* res, const float* g, const float* b_,
                          float* x2, float* xb){
  __shared__ float lx[64*193];
  int bid = blockIdx.x;
  int ot = bid%3, lt = (bid/3)%25, b = bid/75;
  int l0 = lt*64, ob = ot*32;
  const float* src = yz + (b*LL + l0)*DD;
  for (int i=threadIdx.x; i<64*192; i+=256) lx[(i/192)*193 + (i%192)] = src[i];
  __syncthreads();
  int oq = threadIdx.x>>5, lq = threadIdx.x&31;
  float acc[4][2] = {};
  #pragma unroll 4
  for (int c=0;c<192;c++){
    float x0 = lx[lq*193 + c], x1 = lx[(lq+32)*193 + c];
    #pragma unroll
    for (int jo=0;jo<4;jo++){
      float wv = w[(ob+oq+8*jo)*DD + c];
      acc[jo][0] += wv*x0; acc[jo][1] += wv*x1;
    }
  }
  #pragma unroll
  for (int jo=0;jo<4;jo++){
    int o = ob+oq+8*jo;
    float sc = g[o]*BNS, b2 = b_[o];
    #pragma unroll
    for (int jl=0;jl<2;jl++){
      int pos = (b*CC+o)*LL + l0+lq+32*jl;
      float v = res[pos] + acc[jo][jl];
      x2[pos] = v;
      xb[pos] = v*sc + b2;
    }
  }
}

// 15: spatial mean per (b,c)
__global__ void k_gmean(const float* xb, float* gv){
  __shared__ float sm[4];
  int bc = blockIdx.x;
  int tid = threadIdx.x;
  const float* p = xb + bc*LL;
  float s = 0.f;
  for (int l=tid; l<LL; l+=256) s += p[l];
  #pragma unroll
  for (int off=32; off>0; off>>=1) s += __shfl_xor(s, off, 64);
  if ((tid&63)==0) sm[tid>>6] = s;
  __syncthreads();
  if (tid==0) gv[bc] = (sm[0]+sm[1]+sm[2]+sm[3])*(1.0f/LL);
}

// 16: router
__global__ void k_router(const float* gv, const float* rw, const float* rb, float* wm){
  int b = threadIdx.x;
  if (b >= BB) return;
  float lg[EE];
  for (int e=0;e<EE;e++){
    float a = rb[e];
    for (int c=0;c<CC;c++) a += gv[b*CC+c]*rw[e*CC+c];
    lg[e] = a*0.5f;
  }
  float mx = lg[0];
  for (int e=1;e<EE;e++) mx = fmaxf(mx, lg[e]);
  float p[EE], s = 0.f;
  for (int e=0;e<EE;e++){ p[e] = __expf(lg[e]-mx); s += p[e]; }
  for (int e=0;e<EE;e++) p[e] /= s;
  int i1 = 0;
  for (int e=1;e<EE;e++) if (p[e] > p[i1]) i1 = e;
  int i2 = -1;
  for (int e=0;e<EE;e++){ if (e==i1) continue; if (i2<0 || p[e]>p[i2]) i2 = e; }
  float tot = p[i1]+p[i2];
  for (int e=0;e<EE;e++) wm[b*EE+e] = 0.f;
  wm[b*EE+i1] = p[i1]/tot;
  wm[b*EE+i2] = p[i2]/tot;
}

// 17: per-expert dwconv+gelu (skip unselected)
__global__ void k_moedw(const float* xb, const float* dw, const float* db, const float* wm, float* he){
  int idx = blockIdx.x*256 + threadIdx.x;
  if (idx >= EE*BB*CC*LL) return;
  int l = idx%LL, c = (idx/LL)%CC, b = (idx/(LL*CC))%BB, e = idx/(LL*CC*BB);
  if (wm[b*EE+e] == 0.f) return;
  int y = l/40, x0 = l%40;
  const float* ip = xb + (b*CC+c)*LL;
  float acc = 0.f;
  #pragma unroll
  for (int ky=0;ky<3;ky++){
    int yy = y+ky-1; if (yy<0||yy>=40) continue;
    #pragma unroll
    for (int kx=0;kx<3;kx++){
      int xx = x0+kx-1; if (xx<0||xx>=40) continue;
      acc += dw[(e*CC+c)*9+ky*3+kx] * ip[yy*40+xx];
    }
  }
  he[((e*BB+b)*CC+c)*LL+l] = geluf(acc + db[e*CC+c]);
}

// 18: final tiled: out = x2 + sum_e wm*(conv1x1(he_e)+pb_e)
__global__ void k_final(const float* he, const float* pw, const float* pb, const float* wm,
                        const float* x2, void* out, const void* dsraw){
  __shared__ float lx[96*64];
  bool f32 = (((const unsigned*)dsraw)[0] == 0x3F800000u);
  int bid = blockIdx.x;
  int ot = bid%3, lt = (bid/3)%25, b = bid/75;
  int l0 = lt*64, ob = ot*32;
  int oq = threadIdx.x>>5, lq = threadIdx.x&31;
  float acc[4][2] = {};
  float bias[4] = {0.f,0.f,0.f,0.f};
  for (int e=0;e<EE;e++){
    float wv = wm[b*EE+e];
    if (wv == 0.f) continue;
    __syncthreads();
    const float* hb = he + (e*BB+b)*CC*LL;
    for (int i=threadIdx.x; i<96*64; i+=256) lx[i] = hb[(i>>6)*LL + l0 + (i&63)];
    __syncthreads();
    float ae[4][2] = {};
    #pragma unroll 4
    for (int c=0;c<96;c++){
      float x0 = lx[c*64+lq], x1 = lx[c*64+lq+32];
      #pragma unroll
      for (int jo=0;jo<4;jo++){
        float wvw = pw[(e*CC+ob+oq+8*jo)*CC + c];
        ae[jo][0] += wvw*x0; ae[jo][1] += wvw*x1;
      }
    }
    #pragma unroll
    for (int jo=0;jo<4;jo++){
      acc[jo][0] += wv*ae[jo][0];
      acc[jo][1] += wv*ae[jo][1];
      bias[jo] += wv*pb[e*CC+ob+oq+8*jo];
    }
  }
  #pragma unroll
  for (int jo=0;jo<4;jo++){
    int o = ob+oq+8*jo;
    #pragma unroll
    for (int jl=0;jl<2;jl++){
      int pos = (b*CC+o)*LL + l0+lq+32*jl;
      float v = x2[pos] + acc[jo][jl] + bias[jo];
      if (f32) ((float*)out)[pos] = v;
      else     ((bf16*)out)[pos] = __float2bfloat16(v);
    }
  }
}

extern "C" void kernel_launch(void* const* d_in, const int* in_sizes, int n_in,
                              void* d_out, int out_size, void* d_ws, size_t ws_size,
                              hipStream_t stream) {
  static const int cum[34] = {
    0, 614400, 623616, 623712, 623808, 624672, 624768, 624864, 624960,
    634176, 634272, 643488, 643584, 643680, 643776, 680640, 682368, 682560,
    711744, 716352, 717120, 729408, 730176, 730368, 730560, 748992, 749088,
    749184, 749568, 749572, 753028, 753412, 790276, 790660
  };
  float* ws = (float*)d_ws;
  const float* cv[33];
  P33 ps;
  for (int i=0;i<33;i++){ ps.p[i] = d_in[i]; cv[i] = ws + cum[i]; }

  const float* c_x    = cv[0];
  const float* c_pw   = cv[1];
  const float* c_bn0g = cv[2];
  const float* c_bn0b = cv[3];
  const float* c_f1w  = cv[4];
  const float* c_f1b  = cv[5];
  const float* c_lbg  = cv[6];
  const float* c_lbb  = cv[7];
  const float* c_f2w  = cv[8];
  const float* c_f2b  = cv[9];
  const float* c_f3w  = cv[10];
  const float* c_f3b  = cv[11];
  const float* c_n1g  = cv[12];
  const float* c_n1b  = cv[13];
  const float* c_ipw  = cv[14];
  const float* c_cw   = cv[15];
  const float* c_cb   = cv[16];
  const float* c_xpw  = cv[17];
  const float* c_dtw  = cv[18];
  const float* c_dtb  = cv[19];
  const float* c_al   = cv[20];
  const float* c_ds   = cv[21];
  const float* c_ong  = cv[22];
  const float* c_onb  = cv[23];
  const float* c_opw  = cv[24];
  const float* c_n2g  = cv[25];
  const float* c_n2b  = cv[26];
  const float* c_rw   = cv[27];
  const float* c_rb   = cv[28];
  const float* c_mdw  = cv[29];
  const float* c_mdb  = cv[30];
  const float* c_mpw  = cv[31];
  const float* c_mpb  = cv[32];

  // arena (floats), total 13,682,944 = 54.7 MB
  float* R   = ws +   790784;
  float* T1  = ws +  1405184;  // T1 -> X1 -> [XW1] -> X2
  float* X1  = T1;
  float* X2  = T1;
  float* T2  = ws +  2019584;  // T2 -> [XW1] -> XB
  float* XB  = T2;
  float* XW1 = T1;
  float* XXP = ws +  2633984;  // XXP -> Y
  float* Y   = XXP;
  float* Z1  = ws +  3862784;  // z1 (b,l,d)
  float* XX  = ws +  5091584;  // XX -> YZ
  float* YZ  = XX;
  float* XS  = ws +  6320384;  // XS -> HE
  float* HE  = XS;
  float* XD  = ws +  8777984;  // XD (bk,t,38) -> GV/WM
  float* GV  = XD;
  float* WM  = XD + 384;
  float* PB  = ws +  9750784;
  float* SB  = ws + 11716864;

  const int T = 256;
  k_convert  <<<(NTOT+T-1)/T, T, 0, stream>>>(ps, ws);
  k_proj     <<<300, T, 0, stream>>>(c_x, c_pw, c_bn0g, c_bn0b, R);
  k_dwbn     <<<(BB*CC*LL+T-1)/T, T, 0, stream>>>(R, c_f1w, c_f1b, c_lbg, c_lbb, T1);
  k_fc_gelu  <<<300, T, 0, stream>>>(T1, c_f2w, c_f2b, T2);
  k_fc_res_bn<<<300, T, 0, stream>>>(T2, c_f3w, c_f3b, R, c_n1g, c_n1b, X1);
  k_inproj   <<<1200, T, 0, stream>>>(X1, c_ipw, XXP, Z1);
  k_ssconv   <<<(BB*DD*LL+T-1)/T, T, 0, stream>>>(XXP, c_cw, c_cb, XX);
  k_xs       <<<1200, T, 0, stream>>>(XX, XS);
  k_xw       <<<BB*DD, T, 0, stream>>>(XX, XW1);
  hipMemsetAsync(Y, 0, (size_t)BB*DD*LL*sizeof(float), stream);
  k_xdbl     <<<BB*KK*25, T, 0, stream>>>(XX, XW1, c_xpw, XD);
  k_scan1    <<<(BB*KK*NCH*768)/T, T, 0, stream>>>(XS, XD, c_dtw, c_dtb, c_al, PB, SB);
  k_scanmid  <<<(BB*KK*DD*NN+T-1)/T, T, 0, stream>>>(PB, SB);
  k_scan2    <<<(BB*KK*NCH*768)/T, T, 0, stream>>>(XS, XD, c_dtw, c_dtb, c_al, PB, c_ds, Y);
  k_ln       <<<1600, T, 0, stream>>>(Y, c_ong, c_onb, Z1, YZ);
  k_outproj  <<<300, T, 0, stream>>>(YZ, c_opw, R, c_n2g, c_n2b, X2, XB);
  k_gmean    <<<BB*CC, T, 0, stream>>>(XB, GV);
  k_router   <<<1, 64, 0, stream>>>(GV, c_rw, c_rb, WM);
  k_moedw    <<<(EE*BB*CC*LL+T-1)/T, T, 0, stream>>>(XB, c_mdw, c_mdb, WM, HE);
  k_final    <<<300, T, 0, stream>>>(HE, c_mpw, c_mpb, WM, X2, d_out, d_in[21]);
}

// Round 7
// 411.383 us; speedup vs baseline: 2.6787x; 1.0749x over previous
//
#include <hip/hip_runtime.h>
#include <hip/hip_bf16.h>
#include <math.h>

#define BB 4
#define CC 96
#define LL 1600
#define DD 192
#define KK 4
#define RR 6
#define NN 16
#define EE 4
#define NCH 40
#define CLEN 40

typedef __hip_bfloat16 bf16;

__device__ __forceinline__ float geluf(float x){ return 0.5f*x*(1.0f+erff(x*0.70710678118654752440f)); }
__device__ __forceinline__ float softplusf(float x){ return (x>20.0f)? x : __logf(1.0f+__expf(x)); }
#define BNS rsqrtf(1.0f + 1e-5f)
#define LOG2E 1.44269504088896340736f

// hw position for scan-direction k at scan index t
__device__ __forceinline__ int xpos(int k, int l){
  if (k==0) return l;
  if (k==2) return LL-1-l;
  int t = (k==1)? l : (LL-1-l);
  return (t%40)*40 + t/40;   // H==W==40 transpose map (involution)
}

// ---- input conversion: everything -> fp32 in workspace ----
struct P33 { const void* p[33]; };
#define NTOT 790660
__device__ const int g_cum[34] = {
  0, 614400, 623616, 623712, 623808, 624672, 624768, 624864, 624960,
  634176, 634272, 643488, 643584, 643680, 643776, 680640, 682368, 682560,
  711744, 716352, 717120, 729408, 730176, 730368, 730560, 748992, 749088,
  749184, 749568, 749572, 753028, 753412, 790276, 790660
};

__global__ void k_convert(P33 ps, float* cv){
  bool f32 = (((const unsigned*)ps.p[21])[0] == 0x3F800000u);
  int idx = blockIdx.x*256 + threadIdx.x;
  if (idx >= NTOT) return;
  int lo=0, hi=33;
  while (lo+1<hi){ int mid=(lo+hi)>>1; if (idx >= g_cum[mid]) lo=mid; else hi=mid; }
  int local = idx - g_cum[lo];
  float v = f32 ? ((const float*)ps.p[lo])[local]
                : __bfloat162float(((const bf16*)ps.p[lo])[local]);
  cv[idx] = v;
}

// ---------- LDS-tiled 1x1 convs: block = (b, l-tile 64, o-tile 32) ----------
// 1: x = silu(bn0(conv1x1(x, proj_w)))
__global__ void k_proj(const float* x, const float* w, const float* g, const float* b_, float* out){
  __shared__ float lx[96*64];
  int bid = blockIdx.x;
  int ot = bid%3, lt = (bid/3)%25, b = bid/75;
  int l0 = lt*64, ob = ot*32;
  const float* inb = x + b*CC*LL;
  for (int i=threadIdx.x; i<96*64; i+=256) lx[i] = inb[(i>>6)*LL + l0 + (i&63)];
  __syncthreads();
  int oq = threadIdx.x>>5, lq = threadIdx.x&31;
  float acc[4][2] = {};
  #pragma unroll 4
  for (int c=0;c<96;c++){
    float x0 = lx[c*64+lq], x1 = lx[c*64+lq+32];
    #pragma unroll
    for (int jo=0;jo<4;jo++){
      float wv = w[(ob+oq+8*jo)*CC + c];
      acc[jo][0] += wv*x0; acc[jo][1] += wv*x1;
    }
  }
  #pragma unroll
  for (int jo=0;jo<4;jo++){
    int o = ob+oq+8*jo;
    float sc = g[o]*BNS, bb = b_[o];
    #pragma unroll
    for (int jl=0;jl<2;jl++){
      float v = acc[jo][jl]*sc + bb;
      out[(b*CC+o)*LL + l0+lq+32*jl] = v/(1.0f+__expf(-v));
    }
  }
}

// 3: gelu(conv1x1 + bias)
__global__ void k_fc_gelu(const float* in, const float* w, const float* bias, float* out){
  __shared__ float lx[96*64];
  int bid = blockIdx.x;
  int ot = bid%3, lt = (bid/3)%25, b = bid/75;
  int l0 = lt*64, ob = ot*32;
  const float* inb = in + b*CC*LL;
  for (int i=threadIdx.x; i<96*64; i+=256) lx[i] = inb[(i>>6)*LL + l0 + (i&63)];
  __syncthreads();
  int oq = threadIdx.x>>5, lq = threadIdx.x&31;
  float acc[4][2] = {};
  #pragma unroll 4
  for (int c=0;c<96;c++){
    float x0 = lx[c*64+lq], x1 = lx[c*64+lq+32];
    #pragma unroll
    for (int jo=0;jo<4;jo++){
      float wv = w[(ob+oq+8*jo)*CC + c];
      acc[jo][0] += wv*x0; acc[jo][1] += wv*x1;
    }
  }
  #pragma unroll
  for (int jo=0;jo<4;jo++){
    int o = ob+oq+8*jo;
    float bb = bias[o];
    out[(b*CC+o)*LL + l0+lq]    = geluf(acc[jo][0]+bb);
    out[(b*CC+o)*LL + l0+lq+32] = geluf(acc[jo][1]+bb);
  }
}

// 4: X1 = bn_n1( res + conv1x1(in) + bias )
__global__ void k_fc_res_bn(const float* in, const float* w, const float* bias, const float* res,
                            const float* g, const float* b_, float* out){
  __shared__ float lx[96*64];
  int bid = blockIdx.x;
  int ot = bid%3, lt = (bid/3)%25, b = bid/75;
  int l0 = lt*64, ob = ot*32;
  const float* inb = in + b*CC*LL;
  for (int i=threadIdx.x; i<96*64; i+=256) lx[i] = inb[(i>>6)*LL + l0 + (i&63)];
  __syncthreads();
  int oq = threadIdx.x>>5, lq = threadIdx.x&31;
  float acc[4][2] = {};
  #pragma unroll 4
  for (int c=0;c<96;c++){
    float x0 = lx[c*64+lq], x1 = lx[c*64+lq+32];
    #pragma unroll
    for (int jo=0;jo<4;jo++){
      float wv = w[(ob+oq+8*jo)*CC + c];
      acc[jo][0] += wv*x0; acc[jo][1] += wv*x1;
    }
  }
  #pragma unroll
  for (int jo=0;jo<4;jo++){
    int o = ob+oq+8*jo;
    float bb = bias[o], sc = g[o]*BNS, b2 = b_[o];
    #pragma unroll
    for (int jl=0;jl<2;jl++){
      int pos = (b*CC+o)*LL + l0+lq+32*jl;
      float v = acc[jo][jl] + bb + res[pos];
      out[pos] = v*sc + b2;
    }
  }
}

// 5: inproj: 12 o-tiles; tiles 0-5 -> xxp (b,d,l); tiles 6-11 -> z1 (b,l,d) via LDS transpose
__global__ void k_inproj(const float* in, const float* w, float* xxp, float* z1){
  __shared__ float lx[96*64];
  int bid = blockIdx.x;
  int ot = bid%12, lt = (bid/12)%25, b = bid/300;
  int l0 = lt*64, ob = ot*32;
  const float* inb = in + b*CC*LL;
  for (int i=threadIdx.x; i<96*64; i+=256) lx[i] = inb[(i>>6)*LL + l0 + (i&63)];
  __syncthreads();
  int oq = threadIdx.x>>5, lq = threadIdx.x&31;
  float acc[4][2] = {};
  #pragma unroll 4
  for (int c=0;c<96;c++){
    float x0 = lx[c*64+lq], x1 = lx[c*64+lq+32];
    #pragma unroll
    for (int jo=0;jo<4;jo++){
      float wv = w[(ob+oq+8*jo)*CC + c];
      acc[jo][0] += wv*x0; acc[jo][1] += wv*x1;
    }
  }
  if (ot < 6){
    #pragma unroll
    for (int jo=0;jo<4;jo++){
      int oc = ob+oq+8*jo;
      xxp[(b*DD+oc)*LL + l0+lq]    = acc[jo][0];
      xxp[(b*DD+oc)*LL + l0+lq+32] = acc[jo][1];
    }
  } else {
    __syncthreads();
    #pragma unroll
    for (int jo=0;jo<4;jo++){
      int oo = oq+8*jo;
      lx[lq*33 + oo]      = geluf(acc[jo][0]);
      lx[(lq+32)*33 + oo] = geluf(acc[jo][1]);
    }
    __syncthreads();
    int zb = ob - 192;
    for (int i=threadIdx.x; i<64*32; i+=256){
      int u = i>>5, oo = i&31;
      z1[(b*LL + l0+u)*DD + zb + oo] = lx[u*33 + oo];
    }
  }
}

// 6: xx = gelu(dwconv3(xx_pre))
__global__ void k_ssconv(const float* in, const float* w, const float* bias, float* out){
  int idx = blockIdx.x*256 + threadIdx.x;
  if (idx >= BB*DD*LL) return;
  int l = idx%LL, d = (idx/LL)%DD, b = idx/(LL*DD);
  int y = l/40, x0 = l%40;
  const float* ip = in + (b*DD+d)*LL;
  float acc = 0.f;
  #pragma unroll
  for (int ky=0;ky<3;ky++){
    int yy = y+ky-1; if (yy<0||yy>=40) continue;
    #pragma unroll
    for (int kx=0;kx<3;kx++){
      int xx = x0+kx-1; if (xx<0||xx>=40) continue;
      acc += w[d*9+ky*3+kx] * ip[yy*40+xx];
    }
  }
  out[idx] = geluf(acc + bias[d]);
}

// 2: h = bn(dwconv3)
__global__ void k_dwbn(const float* in, const float* w, const float* bias, const float* g, const float* b_, float* out){
  int idx = blockIdx.x*256 + threadIdx.x;
  if (idx >= BB*CC*LL) return;
  int l = idx%LL, c = (idx/LL)%CC, b = idx/(LL*CC);
  int y = l/40, x0 = l%40;
  const float* ip = in + (b*CC+c)*LL;
  float acc = 0.f;
  #pragma unroll
  for (int ky=0;ky<3;ky++){
    int yy = y+ky-1; if (yy<0||yy>=40) continue;
    #pragma unroll
    for (int kx=0;kx<3;kx++){
      int xx = x0+kx-1; if (xx<0||xx>=40) continue;
      acc += w[c*9+ky*3+kx] * ip[yy*40+xx];
    }
  }
  acc += bias[c];
  out[idx] = acc*(g[c]*BNS) + b_[c];
}

// 6b: LDS-tiled transpose -> XS (b,k01,l,d)
__global__ void k_xs(const float* xx, float* xs){
  __shared__ float t[32][33];
  int bid = blockIdx.x;
  int lt = bid % 50, dt = (bid/50)%6, b = bid/300;
  int l0 = lt*32, d0 = dt*32;
  int tx = threadIdx.x & 31, ty = threadIdx.x >> 5;
  #pragma unroll
  for (int j=0;j<4;j++){
    int dd = ty + 8*j;
    t[dd][tx] = xx[(b*DD + d0+dd)*LL + l0 + tx];
  }
  __syncthreads();
  #pragma unroll
  for (int j=0;j<4;j++){
    int ll = ty + 8*j;
    int l = l0 + ll;
    float v = t[tx][ll];
    int lw = (l%40)*40 + l/40;
    xs[((b*2+0)*LL + l )*DD + d0 + tx] = v;
    xs[((b*2+1)*LL + lw)*DD + d0 + tx] = v;
  }
}

// 6c: spatial transpose keeping d-major
__global__ void k_xw(const float* xx, float* xw1){
  __shared__ float sm[40*41];
  int bd = blockIdx.x;
  const float* ip = xx + bd*LL;
  float* op = xw1 + bd*LL;
  for (int i=threadIdx.x; i<LL; i+=256) sm[(i/40)*41 + (i%40)] = ip[i];
  __syncthreads();
  for (int i=threadIdx.x; i<LL; i+=256) op[i] = sm[(i%40)*41 + (i/40)];
}

// 7: xd (bk,t,40) rows = [B(16)|C(16)|dt_r(6)|pad(2)]; block = (bk, 32-t tile)
__global__ void k_xdbl(const float* xx, const float* xw1, const float* w, float* xd){
  __shared__ float lt_[32*41];
  int bid = blockIdx.x;           // BB*KK*50
  int tt = bid % 50, bk = bid / 50;
  int k = bk & 3, b = bk >> 2;
  int t0 = tt*32;
  int cg = threadIdx.x >> 5, tl = threadIdx.x & 31;   // cg 0..7
  int t = t0 + tl;
  int row = (k<2)? t : (LL-1-t);
  const float* base = ((k&1)? xw1 : xx) + b*DD*LL + row;
  const float* wp[5];
  #pragma unroll
  for (int j=0;j<5;j++){
    int c = cg + 8*j; if (c>37) c = 37;
    wp[j] = w + (k*38+c)*DD;
  }
  float acc[5] = {};
  for (int d=0; d<DD; d++){
    float xv = base[d*LL];
    #pragma unroll
    for (int j=0;j<5;j++) acc[j] += wp[j][d]*xv;
  }
  #pragma unroll
  for (int j=0;j<5;j++){
    int c = cg + 8*j;
    if (c < 38) lt_[tl*41 + c] = acc[j];
  }
  __syncthreads();
  float* ob = xd + (bk*LL + t0)*40;
  for (int i=threadIdx.x; i<32*40; i+=256){
    int tr = i/40, col = i%40;
    float v;
    if (col < 32)      v = lt_[tr*41 + col + 6];   // B: c=6..21 -> 0..15 ; C: c=22..37 -> 16..31
    else if (col < 38) v = lt_[tr*41 + col - 32];  // dt_r: c=0..5 -> 32..37
    else               v = 0.f;
    ob[i] = v;
  }
}

// 9: scan pass1 — block = (bk, chunk, 64-d tile); LDS dt; wave = 16d x 4g, 4 states/thread
__global__ void k_scan1(const float* xs, const float* xd, const float* dtw, const float* dtb,
                        const float* Alog, float* Pb, float* Sb){
  __shared__ float ldt[64*41];
  int bid = blockIdx.x;            // BB*KK*NCH*3
  int dt3 = bid % 3;
  int c   = (bid/3) % NCH;
  int bk  = bid/(3*NCH);
  int k = bk & 3, b = bk >> 2;
  int d0 = dt3*64;
  const float* xrow0 = xd + (bk*LL + c*CLEN)*40;
  for (int i=threadIdx.x; i<64*CLEN; i+=256){
    int dd = i/CLEN, j = i%CLEN;
    int kd = k*DD + d0 + dd;
    const float* r = xrow0 + j*40 + 32;
    float dtr = dtb[kd];
    #pragma unroll
    for (int q=0;q<RR;q++) dtr += dtw[kd*RR+q]*r[q];
    ldt[dd*41 + j] = softplusf(dtr);
  }
  __syncthreads();
  int lane = threadIdx.x & 63;
  int d16 = lane & 15, g = lane >> 4;
  int dd = (threadIdx.x>>6)*16 + d16;
  int d = d0 + dd;
  int kd = k*DD + d;
  float A2[4], P[4]={1.f,1.f,1.f,1.f}, S[4]={0.f,0.f,0.f,0.f};
  #pragma unroll
  for (int n=0;n<4;n++) A2[n] = -expf(Alog[kd*NN + g*4 + n])*LOG2E;
  const float* xsb = xs + ((b*2)+(k&1))*LL*DD;
  bool rev = (k>=2);
  int t0 = c*CLEN;
  const float* xr = xrow0;
  for (int j=0;j<CLEN;j++){
    int t = t0+j;
    int row = rev? (LL-1-t) : t;
    float dt = ldt[dd*41 + j];
    float4 B4 = *(const float4*)(xr + g*4);
    float xv = xsb[row*DD + d];
    float u = dt*xv;
    float Ba[4] = {B4.x,B4.y,B4.z,B4.w};
    #pragma unroll
    for (int n=0;n<4;n++){
      float dA = exp2f(dt*A2[n]);
      P[n] *= dA;
      S[n] = S[n]*dA + u*Ba[n];
    }
    xr += 40;
  }
  int off = ((bk*DD + d)*NCH + c)*NN + g*4;
  *(float4*)(Pb+off) = make_float4(P[0],P[1],P[2],P[3]);
  *(float4*)(Sb+off) = make_float4(S[0],S[1],S[2],S[3]);
}

// 10: inter-chunk scan; Hin in-place over Pb
__global__ void k_scanmid(float* Pb, const float* Sb){
  int idx = blockIdx.x*256 + threadIdx.x;
  if (idx >= BB*KK*DD*NN) return;
  int n = idx%NN, bkd = idx/NN;
  float h = 0.f;
  for (int c=0;c<NCH;c++){
    int o = (bkd*NCH + c)*NN + n;
    float p = Pb[o], s = Sb[o];
    Pb[o] = h;
    h = p*h + s;
  }
}

// 11: scan pass2 — same structure; shfl-combine y; atomic into Y (b,l,d)
__global__ void k_scan2(const float* xs, const float* xd, const float* dtw, const float* dtb,
                        const float* Alog, const float* Hin, const float* Ds, float* Y){
  __shared__ float ldt[64*41];
  int bid = blockIdx.x;
  int dt3 = bid % 3;
  int c   = (bid/3) % NCH;
  int bk  = bid/(3*NCH);
  int k = bk & 3, b = bk >> 2;
  int d0 = dt3*64;
  const float* xrow0 = xd + (bk*LL + c*CLEN)*40;
  for (int i=threadIdx.x; i<64*CLEN; i+=256){
    int dd = i/CLEN, j = i%CLEN;
    int kd = k*DD + d0 + dd;
    const float* r = xrow0 + j*40 + 32;
    float dtr = dtb[kd];
    #pragma unroll
    for (int q=0;q<RR;q++) dtr += dtw[kd*RR+q]*r[q];
    ldt[dd*41 + j] = softplusf(dtr);
  }
  __syncthreads();
  int lane = threadIdx.x & 63;
  int d16 = lane & 15, g = lane >> 4;
  int dd = (threadIdx.x>>6)*16 + d16;
  int d = d0 + dd;
  int kd = k*DD + d;
  int off = ((bk*DD + d)*NCH + c)*NN + g*4;
  float4 h4 = *(const float4*)(Hin+off);
  float h[4] = {h4.x, h4.y, h4.z, h4.w};
  float A2[4];
  #pragma unroll
  for (int n=0;n<4;n++) A2[n] = -expf(Alog[kd*NN + g*4 + n])*LOG2E;
  float Dv = Ds[kd];
  const float* xsb = xs + ((b*2)+(k&1))*LL*DD;
  float* yb = Y + b*LL*DD;
  bool rev = (k>=2);
  int t0 = c*CLEN;
  const float* xr = xrow0;
  for (int j=0;j<CLEN;j++){
    int t = t0+j;
    int row = rev? (LL-1-t) : t;
    float dt = ldt[dd*41 + j];
    float4 B4 = *(const float4*)(xr + g*4);
    float4 C4 = *(const float4*)(xr + 16 + g*4);
    float xv = xsb[row*DD + d];
    float u = dt*xv;
    float Ba[4] = {B4.x,B4.y,B4.z,B4.w};
    float Ca[4] = {C4.x,C4.y,C4.z,C4.w};
    float y = 0.f;
    #pragma unroll
    for (int n=0;n<4;n++){
      float dA = exp2f(dt*A2[n]);
      h[n] = h[n]*dA + u*Ba[n];
      y += h[n]*Ca[n];
    }
    y += __shfl_xor(y, 16, 64);
    y += __shfl_xor(y, 32, 64);
    if (g==0){
      int p = xpos(k, t);
      atomicAdd(&yb[p*DD + d], y + Dv*xv);
    }
    xr += 40;
  }
}

// 13: layernorm over d (wave per row), * onorm, * z1(b,l,d) -> YZ (b,l,d)
__global__ void k_ln(const float* Y, const float* og, const float* ob, const float* z1, float* yz){
  int r = blockIdx.x*4 + (threadIdx.x >> 6);
  int lane = threadIdx.x & 63;
  const float* yp = Y + r*DD;
  float v0 = yp[lane], v1 = yp[lane+64], v2 = yp[lane+128];
  float s = v0+v1+v2;
  #pragma unroll
  for (int off=32; off>0; off>>=1) s += __shfl_xor(s, off, 64);
  float m = s*(1.0f/DD);
  float t0=v0-m, t1=v1-m, t2=v2-m;
  float vv = t0*t0+t1*t1+t2*t2;
  #pragma unroll
  for (int off=32; off>0; off>>=1) vv += __shfl_xor(vv, off, 64);
  float rs = rsqrtf(vv*(1.0f/DD) + 1e-5f);
  #pragma unroll
  for (int i=0;i<3;i++){
    int d = lane + 64*i;
    float t = (i==0?t0:(i==1?t1:t2));
    yz[r*DD + d] = (t*rs*og[d] + ob[d]) * z1[r*DD + d];
  }
}

// 14: outproj tiled: input YZ (b,l,d) CIN=192
__global__ void k_outproj(const float* yz, const float* w, const float* res, const float* g, const float* b_,
                          float* x2, float* xb){
  __shared__ float lx[64*193];
  int bid = blockIdx.x;
  int ot = bid%3, lt = (bid/3)%25, b = bid/75;
  int l0 = lt*64, ob = ot*32;
  const float* src = yz + (b*LL + l0)*DD;
  for (int i=threadIdx.x; i<64*192; i+=256) lx[(i/192)*193 + (i%192)] = src[i];
  __syncthreads();
  int oq = threadIdx.x>>5, lq = threadIdx.x&31;
  float acc[4][2] = {};
  #pragma unroll 4
  for (int c=0;c<192;c++){
    float x0 = lx[lq*193 + c], x1 = lx[(lq+32)*193 + c];
    #pragma unroll
    for (int jo=0;jo<4;jo++){
      float wv = w[(ob+oq+8*jo)*DD + c];
      acc[jo][0] += wv*x0; acc[jo][1] += wv*x1;
    }
  }
  #pragma unroll
  for (int jo=0;jo<4;jo++){
    int o = ob+oq+8*jo;
    float sc = g[o]*BNS, b2 = b_[o];
    #pragma unroll
    for (int jl=0;jl<2;jl++){
      int pos = (b*CC+o)*LL + l0+lq+32*jl;
      float v = res[pos] + acc[jo][jl];
      x2[pos] = v;
      xb[pos] = v*sc + b2;
    }
  }
}

// 15: spatial mean per (b,c)
__global__ void k_gmean(const float* xb, float* gv){
  __shared__ float sm[4];
  int bc = blockIdx.x;
  int tid = threadIdx.x;
  const float* p = xb + bc*LL;
  float s = 0.f;
  for (int l=tid; l<LL; l+=256) s += p[l];
  #pragma unroll
  for (int off=32; off>0; off>>=1) s += __shfl_xor(s, off, 64);
  if ((tid&63)==0) sm[tid>>6] = s;
  __syncthreads();
  if (tid==0) gv[bc] = (sm[0]+sm[1]+sm[2]+sm[3])*(1.0f/LL);
}

// 16: router
__global__ void k_router(const float* gv, const float* rw, const float* rb, float* wm){
  int b = threadIdx.x;
  if (b >= BB) return;
  float lg[EE];
  for (int e=0;e<EE;e++){
    float a = rb[e];
    for (int c=0;c<CC;c++) a += gv[b*CC+c]*rw[e*CC+c];
    lg[e] = a*0.5f;
  }
  float mx = lg[0];
  for (int e=1;e<EE;e++) mx = fmaxf(mx, lg[e]);
  float p[EE], s = 0.f;
  for (int e=0;e<EE;e++){ p[e] = __expf(lg[e]-mx); s += p[e]; }
  for (int e=0;e<EE;e++) p[e] /= s;
  int i1 = 0;
  for (int e=1;e<EE;e++) if (p[e] > p[i1]) i1 = e;
  int i2 = -1;
  for (int e=0;e<EE;e++){ if (e==i1) continue; if (i2<0 || p[e]>p[i2]) i2 = e; }
  float tot = p[i1]+p[i2];
  for (int e=0;e<EE;e++) wm[b*EE+e] = 0.f;
  wm[b*EE+i1] = p[i1]/tot;
  wm[b*EE+i2] = p[i2]/tot;
}

// 17: per-expert dwconv+gelu, fused over experts: 9-tap loaded once
__global__ void k_moedw(const float* xb, const float* dw, const float* db, const float* wm, float* he){
  int idx = blockIdx.x*256 + threadIdx.x;
  if (idx >= BB*CC*LL) return;
  int l = idx%LL, c = (idx/LL)%CC, b = idx/(LL*CC);
  int y = l/40, x0 = l%40;
  const float* ip = xb + (b*CC+c)*LL;
  float v[9];
  #pragma unroll
  for (int ky=0;ky<3;ky++){
    #pragma unroll
    for (int kx=0;kx<3;kx++){
      int yy=y+ky-1, xx=x0+kx-1;
      v[ky*3+kx] = (yy<0||yy>=40||xx<0||xx>=40)? 0.f : ip[yy*40+xx];
    }
  }
  #pragma unroll
  for (int e=0;e<EE;e++){
    float wv = wm[b*EE+e];
    if (wv == 0.f) continue;
    const float* wp = dw + (e*CC+c)*9;
    float acc = db[e*CC+c];
    #pragma unroll
    for (int q=0;q<9;q++) acc += wp[q]*v[q];
    he[((e*BB+b)*CC+c)*LL+l] = geluf(acc);
  }
}

// 18: final tiled: out = x2 + sum_e wm*(conv1x1(he_e)+pb_e)
__global__ void k_final(const float* he, const float* pw, const float* pb, const float* wm,
                        const float* x2, void* out, const void* dsraw){
  __shared__ float lx[96*64];
  bool f32 = (((const unsigned*)dsraw)[0] == 0x3F800000u);
  int bid = blockIdx.x;
  int ot = bid%3, lt = (bid/3)%25, b = bid/75;
  int l0 = lt*64, ob = ot*32;
  int oq = threadIdx.x>>5, lq = threadIdx.x&31;
  float acc[4][2] = {};
  float bias[4] = {0.f,0.f,0.f,0.f};
  for (int e=0;e<EE;e++){
    float wv = wm[b*EE+e];
    if (wv == 0.f) continue;
    __syncthreads();
    const float* hb = he + (e*BB+b)*CC*LL;
    for (int i=threadIdx.x; i<96*64; i+=256) lx[i] = hb[(i>>6)*LL + l0 + (i&63)];
    __syncthreads();
    float ae[4][2] = {};
    #pragma unroll 4
    for (int c=0;c<96;c++){
      float x0 = lx[c*64+lq], x1 = lx[c*64+lq+32];
      #pragma unroll
      for (int jo=0;jo<4;jo++){
        float wvw = pw[(e*CC+ob+oq+8*jo)*CC + c];
        ae[jo][0] += wvw*x0; ae[jo][1] += wvw*x1;
      }
    }
    #pragma unroll
    for (int jo=0;jo<4;jo++){
      acc[jo][0] += wv*ae[jo][0];
      acc[jo][1] += wv*ae[jo][1];
      bias[jo] += wv*pb[e*CC+ob+oq+8*jo];
    }
  }
  #pragma unroll
  for (int jo=0;jo<4;jo++){
    int o = ob+oq+8*jo;
    #pragma unroll
    for (int jl=0;jl<2;jl++){
      int pos = (b*CC+o)*LL + l0+lq+32*jl;
      float v = x2[pos] + acc[jo][jl] + bias[jo];
      if (f32) ((float*)out)[pos] = v;
      else     ((bf16*)out)[pos] = __float2bfloat16(v);
    }
  }
}

extern "C" void kernel_launch(void* const* d_in, const int* in_sizes, int n_in,
                              void* d_out, int out_size, void* d_ws, size_t ws_size,
                              hipStream_t stream) {
  static const int cum[34] = {
    0, 614400, 623616, 623712, 623808, 624672, 624768, 624864, 624960,
    634176, 634272, 643488, 643584, 643680, 643776, 680640, 682368, 682560,
    711744, 716352, 717120, 729408, 730176, 730368, 730560, 748992, 749088,
    749184, 749568, 749572, 753028, 753412, 790276, 790660
  };
  float* ws = (float*)d_ws;
  const float* cv[33];
  P33 ps;
  for (int i=0;i<33;i++){ ps.p[i] = d_in[i]; cv[i] = ws + cum[i]; }

  const float* c_x    = cv[0];
  const float* c_pw   = cv[1];
  const float* c_bn0g = cv[2];
  const float* c_bn0b = cv[3];
  const float* c_f1w  = cv[4];
  const float* c_f1b  = cv[5];
  const float* c_lbg  = cv[6];
  const float* c_lbb  = cv[7];
  const float* c_f2w  = cv[8];
  const float* c_f2b  = cv[9];
  const float* c_f3w  = cv[10];
  const float* c_f3b  = cv[11];
  const float* c_n1g  = cv[12];
  const float* c_n1b  = cv[13];
  const float* c_ipw  = cv[14];
  const float* c_cw   = cv[15];
  const float* c_cb   = cv[16];
  const float* c_xpw  = cv[17];
  const float* c_dtw  = cv[18];
  const float* c_dtb  = cv[19];
  const float* c_al   = cv[20];
  const float* c_ds   = cv[21];
  const float* c_ong  = cv[22];
  const float* c_onb  = cv[23];
  const float* c_opw  = cv[24];
  const float* c_n2g  = cv[25];
  const float* c_n2b  = cv[26];
  const float* c_rw   = cv[27];
  const float* c_rb   = cv[28];
  const float* c_mdw  = cv[29];
  const float* c_mdb  = cv[30];
  const float* c_mpw  = cv[31];
  const float* c_mpb  = cv[32];

  // arena (floats), total 13,734,144 = 54.9 MB
  float* R   = ws +   790784;
  float* T1  = ws +  1405184;  // T1 -> X1 -> [XW1] -> X2
  float* X1  = T1;
  float* X2  = T1;
  float* T2  = ws +  2019584;  // T2 -> [XW1] -> XB
  float* XB  = T2;
  float* XW1 = T1;
  float* XXP = ws +  2633984;  // XXP -> Y
  float* Y   = XXP;
  float* Z1  = ws +  3862784;  // z1 (b,l,d)
  float* XX  = ws +  5091584;  // XX -> YZ
  float* YZ  = XX;
  float* XS  = ws +  6320384;  // XS -> HE
  float* HE  = XS;
  float* XD  = ws +  8777984;  // XD (bk,t,40) 1,024,000 -> GV/WM
  float* GV  = XD;
  float* WM  = XD + 384;
  float* PB  = ws +  9801984;  // 1,966,080 (Hin in-place)
  float* SB  = ws + 11768064;  // 1,966,080

  const int T = 256;
  k_convert  <<<(NTOT+T-1)/T, T, 0, stream>>>(ps, ws);
  k_proj     <<<300, T, 0, stream>>>(c_x, c_pw, c_bn0g, c_bn0b, R);
  k_dwbn     <<<(BB*CC*LL+T-1)/T, T, 0, stream>>>(R, c_f1w, c_f1b, c_lbg, c_lbb, T1);
  k_fc_gelu  <<<300, T, 0, stream>>>(T1, c_f2w, c_f2b, T2);
  k_fc_res_bn<<<300, T, 0, stream>>>(T2, c_f3w, c_f3b, R, c_n1g, c_n1b, X1);
  k_inproj   <<<1200, T, 0, stream>>>(X1, c_ipw, XXP, Z1);
  k_ssconv   <<<(BB*DD*LL+T-1)/T, T, 0, stream>>>(XXP, c_cw, c_cb, XX);
  k_xs       <<<1200, T, 0, stream>>>(XX, XS);
  k_xw       <<<BB*DD, T, 0, stream>>>(XX, XW1);
  hipMemsetAsync(Y, 0, (size_t)BB*DD*LL*sizeof(float), stream);
  k_xdbl     <<<BB*KK*50, T, 0, stream>>>(XX, XW1, c_xpw, XD);
  k_scan1    <<<BB*KK*NCH*3, T, 0, stream>>>(XS, XD, c_dtw, c_dtb, c_al, PB, SB);
  k_scanmid  <<<(BB*KK*DD*NN+T-1)/T, T, 0, stream>>>(PB, SB);
  k_scan2    <<<BB*KK*NCH*3, T, 0, stream>>>(XS, XD, c_dtw, c_dtb, c_al, PB, c_ds, Y);
  k_ln       <<<1600, T, 0, stream>>>(Y, c_ong, c_onb, Z1, YZ);
  k_outproj  <<<300, T, 0, stream>>>(YZ, c_opw, R, c_n2g, c_n2b, X2, XB);
  k_gmean    <<<BB*CC, T, 0, stream>>>(XB, GV);
  k_router   <<<1, 64, 0, stream>>>(GV, c_rw, c_rb, WM);
  k_moedw    <<<(BB*CC*LL+T-1)/T, T, 0, stream>>>(XB, c_mdw, c_mdb, WM, HE);
  k_final    <<<300, T, 0, stream>>>(HE, c_mpw, c_mpb, WM, X2, d_out, d_in[21]);
}